// Round 1
// baseline (716.478 us; speedup 1.0000x reference)
//
#include <hip/hip_runtime.h>

typedef unsigned short ushort;
typedef __attribute__((ext_vector_type(8))) __bf16 bf16x8;
typedef __attribute__((ext_vector_type(8))) ushort ushort8;
typedef __attribute__((ext_vector_type(4))) float f32x4;

#define DM 2048
#define NH 16
#define DK 128
#define BATCH 2
#define SEQ 2048
#define MROWS (BATCH*SEQ)   // 4096

#define GLDS16(g, l) __builtin_amdgcn_global_load_lds(                         \
    (const __attribute__((address_space(1))) void*)(g),                        \
    (__attribute__((address_space(3))) void*)(l), 16, 0, 0)

__device__ __forceinline__ ushort f2bf(float f) {
  unsigned u = __builtin_bit_cast(unsigned, f);
  u += 0x7fffu + ((u >> 16) & 1u);
  return (ushort)(u >> 16);
}

// ---------------- f32 -> bf16 convert ----------------
__global__ __launch_bounds__(256) void cvt_kernel(const float* __restrict__ in,
                                                  ushort* __restrict__ out, int n8) {
  int i = blockIdx.x * 256 + threadIdx.x;
  if (i >= n8) return;
  const float4* p = (const float4*)in;
  float4 a = p[2 * i], b = p[2 * i + 1];
  ushort8 o;
  o[0] = f2bf(a.x); o[1] = f2bf(a.y); o[2] = f2bf(a.z); o[3] = f2bf(a.w);
  o[4] = f2bf(b.x); o[5] = f2bf(b.y); o[6] = f2bf(b.z); o[7] = f2bf(b.w);
  *(ushort8*)(out + (size_t)8 * i) = o;
}

// ---------------- GEMM C = A(MxK) * B^T (B is NxK row-major), bf16 in, tile 128x128 ----------------
// MODE 0: write bf16 to (B,H,S,DK) layout. MODE 1: write f32 row-major MxN.
template <int MODE>
__device__ __forceinline__ void gemm_body(const ushort* __restrict__ A,
                                          const ushort* __restrict__ Bm,
                                          ushort* __restrict__ obf,
                                          float* __restrict__ ofp) {
  __shared__ ushort lds_a[128 * 32];
  __shared__ ushort lds_b[128 * 32];
  const int tid = threadIdx.x;
  const int wave = tid >> 6, lane = tid & 63;
  const int l15 = lane & 15, lhi = lane >> 4;
  const int row0 = blockIdx.y * 128, col0 = blockIdx.x * 128;
  const int wr = wave >> 1, wc = wave & 1;

  f32x4 acc[4][4];
  const f32x4 z4 = {0.f, 0.f, 0.f, 0.f};
#pragma unroll
  for (int m = 0; m < 4; ++m)
#pragma unroll
    for (int n = 0; n < 4; ++n) acc[m][n] = z4;

  for (int k0 = 0; k0 < DM; k0 += 32) {
#pragma unroll
    for (int i = 0; i < 2; ++i) {
      int chunk = i * 256 + wave * 64 + lane;
      int r = chunk >> 2, c8 = (chunk & 3) * 8;
      GLDS16(A + (size_t)(row0 + r) * DM + k0 + c8, &lds_a[(i * 256 + wave * 64) * 8]);
      GLDS16(Bm + (size_t)(col0 + r) * DM + k0 + c8, &lds_b[(i * 256 + wave * 64) * 8]);
    }
    __syncthreads();
    bf16x8 af[4], bf[4];
#pragma unroll
    for (int m = 0; m < 4; ++m)
      af[m] = *(const bf16x8*)&lds_a[(wr * 64 + m * 16 + l15) * 32 + lhi * 8];
#pragma unroll
    for (int n = 0; n < 4; ++n)
      bf[n] = *(const bf16x8*)&lds_b[(wc * 64 + n * 16 + l15) * 32 + lhi * 8];
#pragma unroll
    for (int m = 0; m < 4; ++m)
#pragma unroll
      for (int n = 0; n < 4; ++n)
        acc[m][n] = __builtin_amdgcn_mfma_f32_16x16x32_bf16(af[m], bf[n], acc[m][n], 0, 0, 0);
    __syncthreads();
  }
  // epilogue: C row = query row (r), col = output feature (gcol)
#pragma unroll
  for (int m = 0; m < 4; ++m) {
    int grow = row0 + wr * 64 + m * 16 + lhi * 4;
#pragma unroll
    for (int n = 0; n < 4; ++n) {
      int gcol = col0 + wc * 64 + n * 16 + l15;
#pragma unroll
      for (int j = 0; j < 4; ++j) {
        float v = acc[m][n][j];
        int r = grow + j;
        if (MODE == 0) {
          int b = r >> 11, s = r & (SEQ - 1);
          int h = gcol >> 7, d = gcol & (DK - 1);
          obf[((size_t)(b * NH + h) * SEQ + s) * DK + d] = f2bf(v);
        } else {
          ofp[(size_t)r * DM + gcol] = v;
        }
      }
    }
  }
}

__global__ __launch_bounds__(256) void gemm_qkv(const ushort* __restrict__ A,
                                                const ushort* __restrict__ W0,
                                                const ushort* __restrict__ W1,
                                                const ushort* __restrict__ W2,
                                                ushort* __restrict__ O0,
                                                ushort* __restrict__ O1,
                                                ushort* __restrict__ O2) {
  const ushort* Bm = (blockIdx.z == 0) ? W0 : ((blockIdx.z == 1) ? W1 : W2);
  ushort* obf = (blockIdx.z == 0) ? O0 : ((blockIdx.z == 1) ? O1 : O2);
  gemm_body<0>(A, Bm, obf, nullptr);
}

__global__ __launch_bounds__(256) void gemm_out(const ushort* __restrict__ A,
                                                const ushort* __restrict__ Bm,
                                                float* __restrict__ ofp) {
  gemm_body<1>(A, Bm, nullptr, ofp);
}

// ---------------- RoPE in-place on (B,H,S,DK) bf16 ----------------
__global__ __launch_bounds__(256) void rope_kernel(ushort* __restrict__ buf,
                                                   const int* __restrict__ tpos) {
  int idx = blockIdx.x * 256 + threadIdx.x;  // B*NH*S*16 threads
  int c = idx & 15;
  int row = idx >> 4;            // (b*NH+h)*SEQ + s
  int s = row & (SEQ - 1);
  int bh = row >> 11;
  int b = bh >> 4;
  int pos = tpos[b * SEQ + s];
  int d0 = c * 8;
  ushort8 v = *(ushort8*)(buf + (size_t)row * DK + d0);
  float fp = (float)pos;
#pragma unroll
  for (int p = 0; p < 4; ++p) {
    int i = (d0 >> 1) + p;  // pair index 0..63
    float freq = exp2f(-13.287712379549449f * ((float)i * (1.0f / 64.0f)));
    float ang = fp * freq;
    float sn, cs;
    sincosf(ang, &sn, &cs);
    float x1 = __builtin_bit_cast(float, (unsigned)v[2 * p] << 16);
    float x2 = __builtin_bit_cast(float, (unsigned)v[2 * p + 1] << 16);
    float r1 = x1 * cs - x2 * sn;
    float r2 = x1 * sn + x2 * cs;
    v[2 * p] = f2bf(r1);
    v[2 * p + 1] = f2bf(r2);
  }
  *(ushort8*)(buf + (size_t)row * DK + d0) = v;
}

// ---------------- V (B,H,S,DK) -> Vt (B,H,DK,S) ----------------
__global__ __launch_bounds__(256) void transpose_v(const ushort* __restrict__ Vb,
                                                   ushort* __restrict__ Vt) {
  __shared__ ushort t[64 * 80];
  int s0 = blockIdx.x * 64, d0 = blockIdx.y * 64, bh = blockIdx.z;
  const size_t base = (size_t)bh * SEQ * DK;
  int tid = threadIdx.x;
#pragma unroll
  for (int it = 0; it < 2; ++it) {
    int c = it * 256 + tid;
    int r = c >> 3, c8 = (c & 7) * 8;
    ushort8 v = *(const ushort8*)&Vb[base + (size_t)(s0 + r) * DK + d0 + c8];
    *(ushort8*)&t[r * 80 + c8] = v;
  }
  __syncthreads();
  const size_t obase = (size_t)bh * DK * SEQ;
#pragma unroll
  for (int it = 0; it < 2; ++it) {
    int c = it * 256 + tid;
    int dr = c >> 3, sc = (c & 7) * 8;
    ushort8 v;
#pragma unroll
    for (int i2 = 0; i2 < 8; ++i2) v[i2] = t[(sc + i2) * 80 + dr];
    *(ushort8*)&Vt[obase + (size_t)(d0 + dr) * SEQ + s0 + sc] = v;
  }
}

// ---------------- flash attention (causal) ----------------
// grid: (qt=SEQ/64, bh=B*NH). 4 waves, each wave 16 q-rows.
__global__ __launch_bounds__(256) void attn_kernel(const ushort* __restrict__ Qb,
                                                   const ushort* __restrict__ Kb,
                                                   const ushort* __restrict__ Vt,
                                                   ushort* __restrict__ attnb) {
  __shared__ ushort p_lds[4][16][64];
  const int qt = blockIdx.x, bh = blockIdx.y;
  const int tid = threadIdx.x;
  const int w = tid >> 6, lane = tid & 63;
  const int l15 = lane & 15, lhi = lane >> 4;
  const int qbase = qt * 64 + w * 16;
  const size_t qk_base = (size_t)bh * SEQ * DK;
  const size_t v_base = (size_t)bh * DK * SEQ;

  bf16x8 qf[4];
  {
    int qrow = qbase + l15;
#pragma unroll
    for (int ks = 0; ks < 4; ++ks)
      qf[ks] = *(const bf16x8*)&Qb[qk_base + (size_t)qrow * DK + lhi * 8 + ks * 32];
  }
  const f32x4 z4 = {0.f, 0.f, 0.f, 0.f};
  f32x4 acc[8];
#pragma unroll
  for (int n = 0; n < 8; ++n) acc[n] = z4;
  float mrow[4] = {-INFINITY, -INFINITY, -INFINITY, -INFINITY};
  float lrow[4] = {0.f, 0.f, 0.f, 0.f};
  const float scale = 0.08838834764831845f;  // 1/sqrt(128)

  for (int kt = 0; kt <= qt; ++kt) {
    const int kb0 = kt * 64;
    f32x4 sf[4];
#pragma unroll
    for (int nf = 0; nf < 4; ++nf) sf[nf] = z4;
#pragma unroll
    for (int nf = 0; nf < 4; ++nf) {
      int krow = kb0 + nf * 16 + l15;
#pragma unroll
      for (int ks = 0; ks < 4; ++ks) {
        bf16x8 kf = *(const bf16x8*)&Kb[qk_base + (size_t)krow * DK + lhi * 8 + ks * 32];
        sf[nf] = __builtin_amdgcn_mfma_f32_16x16x32_bf16(qf[ks], kf, sf[nf], 0, 0, 0);
      }
    }
    const bool diag = (kt == qt);
#pragma unroll
    for (int nf = 0; nf < 4; ++nf)
#pragma unroll
      for (int j = 0; j < 4; ++j) {
        float v = sf[nf][j] * scale;
        if (diag) {
          int key = kb0 + nf * 16 + l15;
          int q = qbase + lhi * 4 + j;
          if (key > q) v = -INFINITY;
        }
        sf[nf][j] = v;
      }
    float p[4][4];
    float scl[4];
#pragma unroll
    for (int j = 0; j < 4; ++j) {
      float mx = sf[0][j];
#pragma unroll
      for (int nf = 1; nf < 4; ++nf) mx = fmaxf(mx, sf[nf][j]);
      mx = fmaxf(mx, __shfl_xor(mx, 1));
      mx = fmaxf(mx, __shfl_xor(mx, 2));
      mx = fmaxf(mx, __shfl_xor(mx, 4));
      mx = fmaxf(mx, __shfl_xor(mx, 8));
      float mnew = fmaxf(mrow[j], mx);
      float sc = expf(mrow[j] - mnew);
      float rs = 0.f;
#pragma unroll
      for (int nf = 0; nf < 4; ++nf) {
        float e = expf(sf[nf][j] - mnew);
        p[nf][j] = e;
        rs += e;
      }
      rs += __shfl_xor(rs, 1);
      rs += __shfl_xor(rs, 2);
      rs += __shfl_xor(rs, 4);
      rs += __shfl_xor(rs, 8);
      lrow[j] = lrow[j] * sc + rs;
      mrow[j] = mnew;
      scl[j] = sc;
    }
#pragma unroll
    for (int n = 0; n < 8; ++n)
#pragma unroll
      for (int j = 0; j < 4; ++j) acc[n][j] *= scl[j];
    __syncthreads();
#pragma unroll
    for (int nf = 0; nf < 4; ++nf)
#pragma unroll
      for (int j = 0; j < 4; ++j)
        p_lds[w][lhi * 4 + j][nf * 16 + l15] = f2bf(p[nf][j]);
    __syncthreads();
    bf16x8 pa[2];
#pragma unroll
    for (int ks2 = 0; ks2 < 2; ++ks2)
      pa[ks2] = *(const bf16x8*)&p_lds[w][l15][lhi * 8 + ks2 * 32];
#pragma unroll
    for (int n = 0; n < 8; ++n) {
      int d = n * 16 + l15;
#pragma unroll
      for (int ks2 = 0; ks2 < 2; ++ks2) {
        bf16x8 vf = *(const bf16x8*)&Vt[v_base + (size_t)d * SEQ + kb0 + lhi * 8 + ks2 * 32];
        acc[n] = __builtin_amdgcn_mfma_f32_16x16x32_bf16(pa[ks2], vf, acc[n], 0, 0, 0);
      }
    }
  }
  // epilogue -> attnb (B,S,DM) bf16, col = h*DK + d
  const int b = bh >> 4, h = bh & (NH - 1);
#pragma unroll
  for (int n = 0; n < 8; ++n) {
    int d = h * DK + n * 16 + l15;
#pragma unroll
    for (int j = 0; j < 4; ++j) {
      int q = qbase + lhi * 4 + j;
      attnb[((size_t)b * SEQ + q) * DM + d] = f2bf(acc[n][j] / lrow[j]);
    }
  }
}

extern "C" void kernel_launch(void* const* d_in, const int* in_sizes, int n_in,
                              void* d_out, int out_size, void* d_ws, size_t ws_size,
                              hipStream_t stream) {
  const float* x = (const float*)d_in[0];
  const int* tpos = (const int*)d_in[1];
  const float* WQ = (const float*)d_in[2];
  const float* WK = (const float*)d_in[3];
  const float* WV = (const float*)d_in[4];
  const float* WO = (const float*)d_in[5];
  float* out = (float*)d_out;
  char* ws = (char*)d_ws;

  ushort* xb  = (ushort*)(ws + 0);           // 16.8MB; dead after QKV gemm
  ushort* wqb = (ushort*)(ws + 16777216);    // 8.39MB
  ushort* wkb = (ushort*)(ws + 25165824);
  ushort* wvb = (ushort*)(ws + 33554432);
  ushort* wob = (ushort*)(ws + 41943040);
  ushort* Qb  = (ushort*)(ws + 50331648);    // 16.8MB each
  ushort* Kb  = (ushort*)(ws + 67108864);
  ushort* Vb  = (ushort*)(ws + 83886080);
  ushort* Vt  = (ushort*)(ws + 0);           // alias xb (xb dead by then)
  ushort* attnb = (ushort*)(ws + 16777216);  // alias wqb+wkb (dead by then)
  // total ws needed: 100,663,296 bytes

  cvt_kernel<<<4096, 256, 0, stream>>>(x, xb, MROWS * DM / 8);
  cvt_kernel<<<2048, 256, 0, stream>>>(WQ, wqb, DM * DM / 8);
  cvt_kernel<<<2048, 256, 0, stream>>>(WK, wkb, DM * DM / 8);
  cvt_kernel<<<2048, 256, 0, stream>>>(WV, wvb, DM * DM / 8);
  cvt_kernel<<<2048, 256, 0, stream>>>(WO, wob, DM * DM / 8);

  gemm_qkv<<<dim3(DM / 128, MROWS / 128, 3), 256, 0, stream>>>(xb, wqb, wkb, wvb, Qb, Kb, Vb);

  rope_kernel<<<4096, 256, 0, stream>>>(Qb, tpos);
  rope_kernel<<<4096, 256, 0, stream>>>(Kb, tpos);

  transpose_v<<<dim3(SEQ / 64, DK / 64, BATCH * NH), 256, 0, stream>>>(Vb, Vt);

  attn_kernel<<<dim3(SEQ / 64, BATCH * NH), 256, 0, stream>>>(Qb, Kb, Vt, attnb);

  gemm_out<<<dim3(DM / 128, MROWS / 128, 1), 256, 0, stream>>>(attnb, wob, out);
}

// Round 2
// 445.520 us; speedup vs baseline: 1.6082x; 1.6082x over previous
//
#include <hip/hip_runtime.h>

typedef unsigned short ushort;
typedef __attribute__((ext_vector_type(8))) __bf16 bf16x8;
typedef __attribute__((ext_vector_type(8))) ushort ushort8;
typedef __attribute__((ext_vector_type(4))) float f32x4;
typedef __attribute__((ext_vector_type(16))) float f32x16;
typedef __attribute__((ext_vector_type(4))) unsigned u32x4;

#define DM 2048
#define NH 16
#define DK 128
#define BATCH 2
#define SEQ 2048
#define MROWS (BATCH*SEQ)   // 4096

#define GLDS16(g, l) __builtin_amdgcn_global_load_lds(                         \
    (const __attribute__((address_space(1))) void*)(g),                        \
    (__attribute__((address_space(3))) void*)(l), 16, 0, 0)

__device__ __forceinline__ ushort f2bf(float f) {
  unsigned u = __builtin_bit_cast(unsigned, f);
  u += 0x7fffu + ((u >> 16) & 1u);
  return (ushort)(u >> 16);
}

__device__ __forceinline__ unsigned cvtpk(float lo, float hi) {
  unsigned r;
  asm("v_cvt_pk_bf16_f32 %0, %1, %2" : "=v"(r) : "v"(lo), "v"(hi));
  return r;
}

// ---------------- f32 -> bf16 convert ----------------
__global__ __launch_bounds__(256) void cvt_kernel(const float* __restrict__ in,
                                                  ushort* __restrict__ out, int n8) {
  int i = blockIdx.x * 256 + threadIdx.x;
  if (i >= n8) return;
  const float4* p = (const float4*)in;
  float4 a = p[2 * i], b = p[2 * i + 1];
  ushort8 o;
  o[0] = f2bf(a.x); o[1] = f2bf(a.y); o[2] = f2bf(a.z); o[3] = f2bf(a.w);
  o[4] = f2bf(b.x); o[5] = f2bf(b.y); o[6] = f2bf(b.z); o[7] = f2bf(b.w);
  *(ushort8*)(out + (size_t)8 * i) = o;
}

// ---------------- GEMM C = A(MxK) * B^T (B is NxK row-major), bf16 in, tile 128x128 ----------------
// MODE 0: write bf16 to (B,H,S,DK) layout. MODE 1: write f32 row-major MxN.
template <int MODE>
__device__ __forceinline__ void gemm_body(const ushort* __restrict__ A,
                                          const ushort* __restrict__ Bm,
                                          ushort* __restrict__ obf,
                                          float* __restrict__ ofp) {
  __shared__ ushort lds_a[128 * 32];
  __shared__ ushort lds_b[128 * 32];
  const int tid = threadIdx.x;
  const int wave = tid >> 6, lane = tid & 63;
  const int l15 = lane & 15, lhi = lane >> 4;
  const int row0 = blockIdx.y * 128, col0 = blockIdx.x * 128;
  const int wr = wave >> 1, wc = wave & 1;

  f32x4 acc[4][4];
  const f32x4 z4 = {0.f, 0.f, 0.f, 0.f};
#pragma unroll
  for (int m = 0; m < 4; ++m)
#pragma unroll
    for (int n = 0; n < 4; ++n) acc[m][n] = z4;

  for (int k0 = 0; k0 < DM; k0 += 32) {
#pragma unroll
    for (int i = 0; i < 2; ++i) {
      int chunk = i * 256 + wave * 64 + lane;
      int r = chunk >> 2, c8 = (chunk & 3) * 8;
      GLDS16(A + (size_t)(row0 + r) * DM + k0 + c8, &lds_a[(i * 256 + wave * 64) * 8]);
      GLDS16(Bm + (size_t)(col0 + r) * DM + k0 + c8, &lds_b[(i * 256 + wave * 64) * 8]);
    }
    __syncthreads();
    bf16x8 af[4], bf[4];
#pragma unroll
    for (int m = 0; m < 4; ++m)
      af[m] = *(const bf16x8*)&lds_a[(wr * 64 + m * 16 + l15) * 32 + lhi * 8];
#pragma unroll
    for (int n = 0; n < 4; ++n)
      bf[n] = *(const bf16x8*)&lds_b[(wc * 64 + n * 16 + l15) * 32 + lhi * 8];
#pragma unroll
    for (int m = 0; m < 4; ++m)
#pragma unroll
      for (int n = 0; n < 4; ++n)
        acc[m][n] = __builtin_amdgcn_mfma_f32_16x16x32_bf16(af[m], bf[n], acc[m][n], 0, 0, 0);
    __syncthreads();
  }
#pragma unroll
  for (int m = 0; m < 4; ++m) {
    int grow = row0 + wr * 64 + m * 16 + lhi * 4;
#pragma unroll
    for (int n = 0; n < 4; ++n) {
      int gcol = col0 + wc * 64 + n * 16 + l15;
#pragma unroll
      for (int j = 0; j < 4; ++j) {
        float v = acc[m][n][j];
        int r = grow + j;
        if (MODE == 0) {
          int b = r >> 11, s = r & (SEQ - 1);
          int h = gcol >> 7, d = gcol & (DK - 1);
          obf[((size_t)(b * NH + h) * SEQ + s) * DK + d] = f2bf(v);
        } else {
          ofp[(size_t)r * DM + gcol] = v;
        }
      }
    }
  }
}

__global__ __launch_bounds__(256) void gemm_qkv(const ushort* __restrict__ A,
                                                const ushort* __restrict__ W0,
                                                const ushort* __restrict__ W1,
                                                const ushort* __restrict__ W2,
                                                ushort* __restrict__ O0,
                                                ushort* __restrict__ O1,
                                                ushort* __restrict__ O2) {
  const ushort* Bm = (blockIdx.z == 0) ? W0 : ((blockIdx.z == 1) ? W1 : W2);
  ushort* obf = (blockIdx.z == 0) ? O0 : ((blockIdx.z == 1) ? O1 : O2);
  gemm_body<0>(A, Bm, obf, nullptr);
}

__global__ __launch_bounds__(256) void gemm_out(const ushort* __restrict__ A,
                                                const ushort* __restrict__ Bm,
                                                float* __restrict__ ofp) {
  gemm_body<1>(A, Bm, nullptr, ofp);
}

// ---------------- RoPE in-place on (B,H,S,DK) bf16 ----------------
__global__ __launch_bounds__(256) void rope_kernel(ushort* __restrict__ buf,
                                                   const int* __restrict__ tpos) {
  int idx = blockIdx.x * 256 + threadIdx.x;  // B*NH*S*16 threads
  int c = idx & 15;
  int row = idx >> 4;            // (b*NH+h)*SEQ + s
  int s = row & (SEQ - 1);
  int bh = row >> 11;
  int b = bh >> 4;
  int pos = tpos[b * SEQ + s];
  int d0 = c * 8;
  ushort8 v = *(ushort8*)(buf + (size_t)row * DK + d0);
  float fp = (float)pos;
#pragma unroll
  for (int p = 0; p < 4; ++p) {
    int i = (d0 >> 1) + p;  // pair index 0..63
    float freq = exp2f(-13.287712379549449f * ((float)i * (1.0f / 64.0f)));
    float ang = fp * freq;
    float sn, cs;
    sincosf(ang, &sn, &cs);
    float x1 = __builtin_bit_cast(float, (unsigned)v[2 * p] << 16);
    float x2 = __builtin_bit_cast(float, (unsigned)v[2 * p + 1] << 16);
    float r1 = x1 * cs - x2 * sn;
    float r2 = x1 * sn + x2 * cs;
    v[2 * p] = f2bf(r1);
    v[2 * p + 1] = f2bf(r2);
  }
  *(ushort8*)(buf + (size_t)row * DK + d0) = v;
}

// ---------------- V (B,H,S,DK) -> Vt (B,H,DK,S) ----------------
__global__ __launch_bounds__(256) void transpose_v(const ushort* __restrict__ Vb,
                                                   ushort* __restrict__ Vt) {
  __shared__ ushort t[64 * 80];
  int s0 = blockIdx.x * 64, d0 = blockIdx.y * 64, bh = blockIdx.z;
  const size_t base = (size_t)bh * SEQ * DK;
  int tid = threadIdx.x;
#pragma unroll
  for (int it = 0; it < 2; ++it) {
    int c = it * 256 + tid;
    int r = c >> 3, c8 = (c & 7) * 8;
    ushort8 v = *(const ushort8*)&Vb[base + (size_t)(s0 + r) * DK + d0 + c8];
    *(ushort8*)&t[r * 80 + c8] = v;
  }
  __syncthreads();
  const size_t obase = (size_t)bh * DK * SEQ;
#pragma unroll
  for (int it = 0; it < 2; ++it) {
    int c = it * 256 + tid;
    int dr = c >> 3, sc = (c & 7) * 8;
    ushort8 v;
#pragma unroll
    for (int i2 = 0; i2 < 8; ++i2) v[i2] = t[(sc + i2) * 80 + dr];
    *(ushort8*)&Vt[obase + (size_t)(d0 + dr) * SEQ + s0 + sc] = v;
  }
}

// ---------------- flash attention (causal), swapped-operand 32x32 ----------------
// 1 wave per block, 32 q-rows per wave. grid: (SEQ/32 qtiles reversed, B*NH).
// S^T = mfma(K_frag, Q_frag): lane owns q = qbase + (lane&31); softmax lane-local
// except one shfl_xor(32). P re-layout to PV B-operand via cvt_pk + xor-32 exchange.
__global__ __launch_bounds__(64, 2) void attn_kernel(const ushort* __restrict__ Qb,
                                                     const ushort* __restrict__ Kb,
                                                     const ushort* __restrict__ Vt,
                                                     ushort* __restrict__ attnb) {
  __shared__ ushort lds_o[32][136];
  const int qt = (int)gridDim.x - 1 - (int)blockIdx.x;  // longest first
  const int bh = blockIdx.y;
  const int lane = threadIdx.x;
  const int l31 = lane & 31, hi = lane >> 5;
  const int qbase = qt * 32;
  const int q = qbase + l31;
  const size_t qk_base = (size_t)bh * SEQ * DK;
  const size_t v_base = (size_t)bh * DK * SEQ;

  // Q fragments (B-operand): lane holds Q[q][d = ks*16 + hi*8 + e]
  bf16x8 qf[8];
#pragma unroll
  for (int ks = 0; ks < 8; ++ks)
    qf[ks] = *(const bf16x8*)&Qb[qk_base + (size_t)q * DK + ks * 16 + hi * 8];

  f32x16 acc[4];
#pragma unroll
  for (int dt = 0; dt < 4; ++dt)
#pragma unroll
    for (int r = 0; r < 16; ++r) acc[dt][r] = 0.f;

  float m2 = -INFINITY, lsum = 0.f;
  const float cs2 = 0.08838834764831845f * 1.4426950408889634f;  // (1/sqrt(128))*log2(e)

  for (int kb0 = 0; kb0 <= qbase; kb0 += 32) {
    // --- QK^T (swapped): S^T[k][q], lane holds s[r]=S[q][k=kb0+crow(r,hi)]
    f32x16 s;
#pragma unroll
    for (int r = 0; r < 16; ++r) s[r] = 0.f;
#pragma unroll
    for (int ks = 0; ks < 8; ++ks) {
      bf16x8 kf = *(const bf16x8*)&Kb[qk_base + (size_t)(kb0 + l31) * DK + ks * 16 + hi * 8];
      s = __builtin_amdgcn_mfma_f32_32x32x16_bf16(kf, qf[ks], s, 0, 0, 0);
    }
    // --- scale + causal mask + online softmax (lane-local row)
    const bool diag = (kb0 == qbase);
    float mx = -INFINITY;
#pragma unroll
    for (int r = 0; r < 16; ++r) {
      float t = s[r] * cs2;
      if (diag) {
        int kk = kb0 + (r & 3) + 8 * (r >> 2) + 4 * hi;
        if (kk > q) t = -INFINITY;
      }
      s[r] = t;
      mx = fmaxf(mx, t);
    }
    mx = fmaxf(mx, __shfl_xor(mx, 32));
    float mnew = fmaxf(m2, mx);
    float sc = exp2f(m2 - mnew);
    m2 = mnew;
    float rs = 0.f;
#pragma unroll
    for (int r = 0; r < 16; ++r) {
      float p = exp2f(s[r] - mnew);
      s[r] = p;
      rs += p;
    }
    rs += __shfl_xor(rs, 32);
    lsum = lsum * sc + rs;
#pragma unroll
    for (int dt = 0; dt < 4; ++dt)
#pragma unroll
      for (int r = 0; r < 16; ++r) acc[dt][r] *= sc;
    // --- pack P to bf16 and build PV B-operand fragments (k = 16*ks + hi*8 + e)
    unsigned w[8], wsw[8];
#pragma unroll
    for (int i = 0; i < 8; ++i) w[i] = cvtpk(s[2 * i], s[2 * i + 1]);
#pragma unroll
    for (int i = 0; i < 8; ++i) wsw[i] = (unsigned)__shfl_xor((int)w[i], 32);
    u32x4 b0, b1;
    b0[0] = hi ? wsw[2] : w[0];
    b0[1] = hi ? wsw[3] : w[1];
    b0[2] = hi ? w[2] : wsw[0];
    b0[3] = hi ? w[3] : wsw[1];
    b1[0] = hi ? wsw[6] : w[4];
    b1[1] = hi ? wsw[7] : w[5];
    b1[2] = hi ? w[6] : wsw[4];
    b1[3] = hi ? w[7] : wsw[5];
    bf16x8 pb0 = __builtin_bit_cast(bf16x8, b0);
    bf16x8 pb1 = __builtin_bit_cast(bf16x8, b1);
    // --- PV (swapped): O^T[d][q] += V^T[d][k] * P^T[k][q]
#pragma unroll
    for (int dt = 0; dt < 4; ++dt) {
      bf16x8 vf0 = *(const bf16x8*)&Vt[v_base + (size_t)(dt * 32 + l31) * SEQ + kb0 + hi * 8];
      bf16x8 vf1 = *(const bf16x8*)&Vt[v_base + (size_t)(dt * 32 + l31) * SEQ + kb0 + 16 + hi * 8];
      acc[dt] = __builtin_amdgcn_mfma_f32_32x32x16_bf16(vf0, pb0, acc[dt], 0, 0, 0);
      acc[dt] = __builtin_amdgcn_mfma_f32_32x32x16_bf16(vf1, pb1, acc[dt], 0, 0, 0);
    }
  }
  // --- epilogue: normalize, transpose via LDS, coalesced store
  float inv = 1.0f / lsum;
#pragma unroll
  for (int dt = 0; dt < 4; ++dt)
#pragma unroll
    for (int rq = 0; rq < 4; ++rq) {
      unsigned lo = cvtpk(acc[dt][4 * rq] * inv, acc[dt][4 * rq + 1] * inv);
      unsigned hh = cvtpk(acc[dt][4 * rq + 2] * inv, acc[dt][4 * rq + 3] * inv);
      uint2 pr; pr.x = lo; pr.y = hh;
      *(uint2*)&lds_o[l31][dt * 32 + rq * 8 + hi * 4] = pr;
    }
  __syncthreads();
  const int b = bh >> 4, h = bh & (NH - 1);
#pragma unroll
  for (int it = 0; it < 8; ++it) {
    int row = it * 4 + (lane >> 4);
    int c8 = (lane & 15) * 8;
    ushort8 v = *(const ushort8*)&lds_o[row][c8];
    *(ushort8*)&attnb[((size_t)b * SEQ + qbase + row) * DM + h * DK + c8] = v;
  }
}

extern "C" void kernel_launch(void* const* d_in, const int* in_sizes, int n_in,
                              void* d_out, int out_size, void* d_ws, size_t ws_size,
                              hipStream_t stream) {
  const float* x = (const float*)d_in[0];
  const int* tpos = (const int*)d_in[1];
  const float* WQ = (const float*)d_in[2];
  const float* WK = (const float*)d_in[3];
  const float* WV = (const float*)d_in[4];
  const float* WO = (const float*)d_in[5];
  float* out = (float*)d_out;
  char* ws = (char*)d_ws;

  ushort* xb  = (ushort*)(ws + 0);           // 16.8MB; dead after QKV gemm
  ushort* wqb = (ushort*)(ws + 16777216);    // 8.39MB
  ushort* wkb = (ushort*)(ws + 25165824);
  ushort* wvb = (ushort*)(ws + 33554432);
  ushort* wob = (ushort*)(ws + 41943040);
  ushort* Qb  = (ushort*)(ws + 50331648);    // 16.8MB each
  ushort* Kb  = (ushort*)(ws + 67108864);
  ushort* Vb  = (ushort*)(ws + 83886080);
  ushort* Vt  = (ushort*)(ws + 0);           // alias xb (xb dead by then)
  ushort* attnb = (ushort*)(ws + 16777216);  // alias wqb+wkb (dead by then)

  cvt_kernel<<<4096, 256, 0, stream>>>(x, xb, MROWS * DM / 8);
  cvt_kernel<<<2048, 256, 0, stream>>>(WQ, wqb, DM * DM / 8);
  cvt_kernel<<<2048, 256, 0, stream>>>(WK, wkb, DM * DM / 8);
  cvt_kernel<<<2048, 256, 0, stream>>>(WV, wvb, DM * DM / 8);
  cvt_kernel<<<2048, 256, 0, stream>>>(WO, wob, DM * DM / 8);

  gemm_qkv<<<dim3(DM / 128, MROWS / 128, 3), 256, 0, stream>>>(xb, wqb, wkb, wvb, Qb, Kb, Vb);

  rope_kernel<<<4096, 256, 0, stream>>>(Qb, tpos);
  rope_kernel<<<4096, 256, 0, stream>>>(Kb, tpos);

  transpose_v<<<dim3(SEQ / 64, DK / 64, BATCH * NH), 256, 0, stream>>>(Vb, Vt);

  attn_kernel<<<dim3(SEQ / 32, BATCH * NH), 64, 0, stream>>>(Qb, Kb, Vt, attnb);

  gemm_out<<<dim3(DM / 128, MROWS / 128, 1), 256, 0, stream>>>(attnb, wob, out);
}

// Round 3
// 302.613 us; speedup vs baseline: 2.3676x; 1.4722x over previous
//
#include <hip/hip_runtime.h>

typedef unsigned short ushort;
typedef __attribute__((ext_vector_type(8))) __bf16 bf16x8;
typedef __attribute__((ext_vector_type(8))) ushort ushort8;
typedef __attribute__((ext_vector_type(4))) float f32x4;
typedef __attribute__((ext_vector_type(16))) float f32x16;
typedef __attribute__((ext_vector_type(4))) unsigned u32x4;

#define DM 2048
#define NH 16
#define DK 128
#define BATCH 2
#define SEQ 2048
#define MROWS (BATCH*SEQ)   // 4096

#define GLDS16(g, l) __builtin_amdgcn_global_load_lds(                         \
    (const __attribute__((address_space(1))) void*)(g),                        \
    (__attribute__((address_space(3))) void*)(l), 16, 0, 0)

__device__ __forceinline__ ushort f2bf(float f) {
  unsigned u = __builtin_bit_cast(unsigned, f);
  u += 0x7fffu + ((u >> 16) & 1u);
  return (ushort)(u >> 16);
}

__device__ __forceinline__ unsigned cvtpk(float lo, float hi) {
  unsigned r;
  asm("v_cvt_pk_bf16_f32 %0, %1, %2" : "=v"(r) : "v"(lo), "v"(hi));
  return r;
}

// ---------------- f32 -> bf16 convert ----------------
__global__ __launch_bounds__(256) void cvt_kernel(const float* __restrict__ in,
                                                  ushort* __restrict__ out, int n8) {
  int i = blockIdx.x * 256 + threadIdx.x;
  if (i >= n8) return;
  const float4* p = (const float4*)in;
  float4 a = p[2 * i], b = p[2 * i + 1];
  ushort8 o;
  o[0] = f2bf(a.x); o[1] = f2bf(a.y); o[2] = f2bf(a.z); o[3] = f2bf(a.w);
  o[4] = f2bf(b.x); o[5] = f2bf(b.y); o[6] = f2bf(b.z); o[7] = f2bf(b.w);
  *(ushort8*)(out + (size_t)8 * i) = o;
}

// ---------------- GEMM C = A(MxK) * B^T (B is NxK row-major), bf16 in, tile 128x128 ----------------
template <int MODE>
__device__ __forceinline__ void gemm_body(const ushort* __restrict__ A,
                                          const ushort* __restrict__ Bm,
                                          ushort* __restrict__ obf,
                                          float* __restrict__ ofp) {
  __shared__ ushort lds_a[128 * 32];
  __shared__ ushort lds_b[128 * 32];
  const int tid = threadIdx.x;
  const int wave = tid >> 6, lane = tid & 63;
  const int l15 = lane & 15, lhi = lane >> 4;
  const int row0 = blockIdx.y * 128, col0 = blockIdx.x * 128;
  const int wr = wave >> 1, wc = wave & 1;

  f32x4 acc[4][4];
  const f32x4 z4 = {0.f, 0.f, 0.f, 0.f};
#pragma unroll
  for (int m = 0; m < 4; ++m)
#pragma unroll
    for (int n = 0; n < 4; ++n) acc[m][n] = z4;

  for (int k0 = 0; k0 < DM; k0 += 32) {
#pragma unroll
    for (int i = 0; i < 2; ++i) {
      int chunk = i * 256 + wave * 64 + lane;
      int r = chunk >> 2, c8 = (chunk & 3) * 8;
      GLDS16(A + (size_t)(row0 + r) * DM + k0 + c8, &lds_a[(i * 256 + wave * 64) * 8]);
      GLDS16(Bm + (size_t)(col0 + r) * DM + k0 + c8, &lds_b[(i * 256 + wave * 64) * 8]);
    }
    __syncthreads();
    bf16x8 af[4], bf[4];
#pragma unroll
    for (int m = 0; m < 4; ++m)
      af[m] = *(const bf16x8*)&lds_a[(wr * 64 + m * 16 + l15) * 32 + lhi * 8];
#pragma unroll
    for (int n = 0; n < 4; ++n)
      bf[n] = *(const bf16x8*)&lds_b[(wc * 64 + n * 16 + l15) * 32 + lhi * 8];
#pragma unroll
    for (int m = 0; m < 4; ++m)
#pragma unroll
      for (int n = 0; n < 4; ++n)
        acc[m][n] = __builtin_amdgcn_mfma_f32_16x16x32_bf16(af[m], bf[n], acc[m][n], 0, 0, 0);
    __syncthreads();
  }
#pragma unroll
  for (int m = 0; m < 4; ++m) {
    int grow = row0 + wr * 64 + m * 16 + lhi * 4;
#pragma unroll
    for (int n = 0; n < 4; ++n) {
      int gcol = col0 + wc * 64 + n * 16 + l15;
#pragma unroll
      for (int j = 0; j < 4; ++j) {
        float v = acc[m][n][j];
        int r = grow + j;
        if (MODE == 0) {
          int b = r >> 11, s = r & (SEQ - 1);
          int h = gcol >> 7, d = gcol & (DK - 1);
          obf[((size_t)(b * NH + h) * SEQ + s) * DK + d] = f2bf(v);
        } else {
          ofp[(size_t)r * DM + gcol] = v;
        }
      }
    }
  }
}

__global__ __launch_bounds__(256) void gemm_qkv(const ushort* __restrict__ A,
                                                const ushort* __restrict__ W0,
                                                const ushort* __restrict__ W1,
                                                const ushort* __restrict__ W2,
                                                ushort* __restrict__ O0,
                                                ushort* __restrict__ O1,
                                                ushort* __restrict__ O2) {
  const ushort* Bm = (blockIdx.z == 0) ? W0 : ((blockIdx.z == 1) ? W1 : W2);
  ushort* obf = (blockIdx.z == 0) ? O0 : ((blockIdx.z == 1) ? O1 : O2);
  gemm_body<0>(A, Bm, obf, nullptr);
}

__global__ __launch_bounds__(256) void gemm_out(const ushort* __restrict__ A,
                                                const ushort* __restrict__ Bm,
                                                float* __restrict__ ofp) {
  gemm_body<1>(A, Bm, nullptr, ofp);
}

// ---------------- RoPE in-place on (B,H,S,DK) bf16 ----------------
__global__ __launch_bounds__(256) void rope_kernel(ushort* __restrict__ buf,
                                                   const int* __restrict__ tpos) {
  int idx = blockIdx.x * 256 + threadIdx.x;
  int c = idx & 15;
  int row = idx >> 4;
  int s = row & (SEQ - 1);
  int bh = row >> 11;
  int b = bh >> 4;
  int pos = tpos[b * SEQ + s];
  int d0 = c * 8;
  ushort8 v = *(ushort8*)(buf + (size_t)row * DK + d0);
  float fp = (float)pos;
#pragma unroll
  for (int p = 0; p < 4; ++p) {
    int i = (d0 >> 1) + p;
    float freq = exp2f(-13.287712379549449f * ((float)i * (1.0f / 64.0f)));
    float ang = fp * freq;
    float sn, cs;
    sincosf(ang, &sn, &cs);
    float x1 = __builtin_bit_cast(float, (unsigned)v[2 * p] << 16);
    float x2 = __builtin_bit_cast(float, (unsigned)v[2 * p + 1] << 16);
    float r1 = x1 * cs - x2 * sn;
    float r2 = x1 * sn + x2 * cs;
    v[2 * p] = f2bf(r1);
    v[2 * p + 1] = f2bf(r2);
  }
  *(ushort8*)(buf + (size_t)row * DK + d0) = v;
}

// ---------------- V (B,H,S,DK) -> Vt (B,H,DK,S) ----------------
__global__ __launch_bounds__(256) void transpose_v(const ushort* __restrict__ Vb,
                                                   ushort* __restrict__ Vt) {
  __shared__ ushort t[64 * 80];
  int s0 = blockIdx.x * 64, d0 = blockIdx.y * 64, bh = blockIdx.z;
  const size_t base = (size_t)bh * SEQ * DK;
  int tid = threadIdx.x;
#pragma unroll
  for (int it = 0; it < 2; ++it) {
    int c = it * 256 + tid;
    int r = c >> 3, c8 = (c & 7) * 8;
    ushort8 v = *(const ushort8*)&Vb[base + (size_t)(s0 + r) * DK + d0 + c8];
    *(ushort8*)&t[r * 80 + c8] = v;
  }
  __syncthreads();
  const size_t obase = (size_t)bh * DK * SEQ;
#pragma unroll
  for (int it = 0; it < 2; ++it) {
    int c = it * 256 + tid;
    int dr = c >> 3, sc = (c & 7) * 8;
    ushort8 v;
#pragma unroll
    for (int i2 = 0; i2 < 8; ++i2) v[i2] = t[(sc + i2) * 80 + dr];
    *(ushort8*)&Vt[obase + (size_t)(d0 + dr) * SEQ + s0 + sc] = v;
  }
}

// ---------------- flash attention (causal), 4 waves/block, LDS-staged KV ----------------
// QBLK=128 (32 q-rows/wave), KVBLK=64, double-buffered K + V^T tiles in LDS.
// Swapped-operand 32x32 MFMA; XOR-swizzled LDS (linear dest + pre-swizzled
// global source for global_load_lds, swizzled ds_read). Grid: 512 blocks,
// qt paired with 15-qt across halves for causal load balance.
__global__ __launch_bounds__(256, 2) void attn_kernel(const ushort* __restrict__ Qb,
                                                      const ushort* __restrict__ Kb,
                                                      const ushort* __restrict__ Vt,
                                                      ushort* __restrict__ attnb) {
  __shared__ ushort lds[32768];  // K bufs @0,8192; V^T bufs @16384,24576 (ushort idx)
  const int bx = blockIdx.x;
  const int u = bx & 255, hg = bx >> 8;
  const int qt = hg ? (15 - (u & 15)) : (u & 15);
  const int bh = (u >> 4) + hg * 16;
  const int tid = threadIdx.x;
  const int w = tid >> 6, lane = tid & 63;
  const int l31 = lane & 31, hi = lane >> 5;
  const int qb = qt * 128;
  const int qsb = qb + w * 32;  // wave's q-strip base
  const int q = qsb + l31;
  const size_t qk_base = (size_t)bh * SEQ * DK;
  const size_t v_base = (size_t)bh * DK * SEQ;
  const int nt = (qb + 128) >> 6;

  bf16x8 qf[8];
#pragma unroll
  for (int ks = 0; ks < 8; ++ks)
    qf[ks] = *(const bf16x8*)&Qb[qk_base + (size_t)q * DK + ks * 16 + hi * 8];

  f32x16 acc[4];
#pragma unroll
  for (int dt = 0; dt < 4; ++dt)
#pragma unroll
    for (int r = 0; r < 16; ++r) acc[dt][r] = 0.f;

  float m2 = -INFINITY, lsum = 0.f;
  const float cs2 = 0.08838834764831845f * 1.4426950408889634f;  // (1/sqrt(128))*log2(e)

  auto stage = [&](int t, int bufsel) {
    const int kb0 = t * 64;
    // K tile: 64 rows x 128 cols bf16 = 1024 16B-granules; lds[row][c16] holds
    // global granule (c16 ^ (row&7)).
#pragma unroll
    for (int i = 0; i < 4; ++i) {
      int g = w * 256 + i * 64 + lane;
      int row = g >> 4, c16 = g & 15;
      GLDS16(Kb + qk_base + (size_t)(kb0 + row) * DK + ((c16 ^ (row & 7)) * 8),
             &lds[bufsel * 8192 + (w * 256 + i * 64) * 8]);
    }
    // V^T tile: 128 rows x 64 cols = 1024 granules; lds[row][c8] holds (c8 ^ (row&7)).
#pragma unroll
    for (int i = 0; i < 4; ++i) {
      int g = w * 256 + i * 64 + lane;
      int row = g >> 3, c8 = g & 7;
      GLDS16(Vt + v_base + (size_t)row * SEQ + kb0 + ((c8 ^ (row & 7)) * 8),
             &lds[16384 + bufsel * 8192 + (w * 256 + i * 64) * 8]);
    }
  };

  stage(0, 0);
  __syncthreads();
  int buf = 0;

  for (int t = 0; t < nt; ++t) {
    if (t + 1 < nt) stage(t + 1, buf ^ 1);
    const int kb0 = t * 64;
    if (kb0 <= qsb) {
      const ushort* lk = &lds[buf * 8192];
      const ushort* lv = &lds[16384 + buf * 8192];
      const int kb1 = kb0 + 32;
      const bool diag0 = (kb0 == qsb);
      const bool have1 = (kb1 <= qsb);
      const bool diag1 = (kb1 == qsb);
      const int sw = l31 & 7;

      f32x16 s0, s1;
#pragma unroll
      for (int r = 0; r < 16; ++r) { s0[r] = 0.f; s1[r] = 0.f; }
      __builtin_amdgcn_s_setprio(1);
#pragma unroll
      for (int ks = 0; ks < 8; ++ks) {
        int g = 2 * ks + hi;
        bf16x8 kf = *(const bf16x8*)&lk[(l31 * 16 + (g ^ sw)) * 8];
        s0 = __builtin_amdgcn_mfma_f32_32x32x16_bf16(kf, qf[ks], s0, 0, 0, 0);
      }
      if (have1) {
#pragma unroll
        for (int ks = 0; ks < 8; ++ks) {
          int g = 2 * ks + hi;
          bf16x8 kf = *(const bf16x8*)&lk[((32 + l31) * 16 + (g ^ sw)) * 8];
          s1 = __builtin_amdgcn_mfma_f32_32x32x16_bf16(kf, qf[ks], s1, 0, 0, 0);
        }
      }
      __builtin_amdgcn_s_setprio(0);

      // scale + mask + row max (lane-local; pair merge via xor-32)
      float mx = -INFINITY;
#pragma unroll
      for (int r = 0; r < 16; ++r) {
        float v = s0[r] * cs2;
        if (diag0) {
          int kk = kb0 + (r & 3) + 8 * (r >> 2) + 4 * hi;
          if (kk > q) v = -INFINITY;
        }
        s0[r] = v;
        mx = fmaxf(mx, v);
      }
      if (have1) {
#pragma unroll
        for (int r = 0; r < 16; ++r) {
          float v = s1[r] * cs2;
          if (diag1) {
            int kk = kb1 + (r & 3) + 8 * (r >> 2) + 4 * hi;
            if (kk > q) v = -INFINITY;
          }
          s1[r] = v;
          mx = fmaxf(mx, v);
        }
      }
      mx = fmaxf(mx, __shfl_xor(mx, 32));

      float sc = 1.f;
      if (!__all(mx <= m2 + 11.5f)) {  // defer-max (T13), THR = 8*log2(e)
        float mnew = fmaxf(m2, mx);
        sc = exp2f(m2 - mnew);
        m2 = mnew;
#pragma unroll
        for (int dt = 0; dt < 4; ++dt)
#pragma unroll
          for (int r = 0; r < 16; ++r) acc[dt][r] *= sc;
      }
      float rs = 0.f;
#pragma unroll
      for (int r = 0; r < 16; ++r) {
        float p = exp2f(s0[r] - m2);
        s0[r] = p;
        rs += p;
      }
      if (have1) {
#pragma unroll
        for (int r = 0; r < 16; ++r) {
          float p = exp2f(s1[r] - m2);
          s1[r] = p;
          rs += p;
        }
      }
      rs += __shfl_xor(rs, 32);
      lsum = lsum * sc + rs;

      // pack P -> bf16 PV B-operands (cvt_pk + xor-32 exchange)
      unsigned w0[8], ws0[8];
#pragma unroll
      for (int i = 0; i < 8; ++i) w0[i] = cvtpk(s0[2 * i], s0[2 * i + 1]);
#pragma unroll
      for (int i = 0; i < 8; ++i) ws0[i] = (unsigned)__shfl_xor((int)w0[i], 32);
      u32x4 b00, b01;
      b00[0] = hi ? ws0[2] : w0[0]; b00[1] = hi ? ws0[3] : w0[1];
      b00[2] = hi ? w0[2] : ws0[0]; b00[3] = hi ? w0[3] : ws0[1];
      b01[0] = hi ? ws0[6] : w0[4]; b01[1] = hi ? ws0[7] : w0[5];
      b01[2] = hi ? w0[6] : ws0[4]; b01[3] = hi ? w0[7] : ws0[5];
      bf16x8 pb00 = __builtin_bit_cast(bf16x8, b00);
      bf16x8 pb01 = __builtin_bit_cast(bf16x8, b01);
      bf16x8 pb10, pb11;
      if (have1) {
        unsigned w1[8], ws1[8];
#pragma unroll
        for (int i = 0; i < 8; ++i) w1[i] = cvtpk(s1[2 * i], s1[2 * i + 1]);
#pragma unroll
        for (int i = 0; i < 8; ++i) ws1[i] = (unsigned)__shfl_xor((int)w1[i], 32);
        u32x4 b10, b11;
        b10[0] = hi ? ws1[2] : w1[0]; b10[1] = hi ? ws1[3] : w1[1];
        b10[2] = hi ? w1[2] : ws1[0]; b10[3] = hi ? w1[3] : ws1[1];
        b11[0] = hi ? ws1[6] : w1[4]; b11[1] = hi ? ws1[7] : w1[5];
        b11[2] = hi ? w1[6] : ws1[4]; b11[3] = hi ? w1[7] : ws1[5];
        pb10 = __builtin_bit_cast(bf16x8, b10);
        pb11 = __builtin_bit_cast(bf16x8, b11);
      }

      // PV: O^T[d][q] += V^T[d][k] * P^T[k][q]
      __builtin_amdgcn_s_setprio(1);
#pragma unroll
      for (int dt = 0; dt < 4; ++dt) {
        int vr = (dt * 32 + l31) * 8;
        bf16x8 vf0 = *(const bf16x8*)&lv[(vr + ((0 + hi) ^ sw)) * 8];
        bf16x8 vf1 = *(const bf16x8*)&lv[(vr + ((2 + hi) ^ sw)) * 8];
        acc[dt] = __builtin_amdgcn_mfma_f32_32x32x16_bf16(vf0, pb00, acc[dt], 0, 0, 0);
        acc[dt] = __builtin_amdgcn_mfma_f32_32x32x16_bf16(vf1, pb01, acc[dt], 0, 0, 0);
        if (have1) {
          bf16x8 vf2 = *(const bf16x8*)&lv[(vr + ((4 + hi) ^ sw)) * 8];
          bf16x8 vf3 = *(const bf16x8*)&lv[(vr + ((6 + hi) ^ sw)) * 8];
          acc[dt] = __builtin_amdgcn_mfma_f32_32x32x16_bf16(vf2, pb10, acc[dt], 0, 0, 0);
          acc[dt] = __builtin_amdgcn_mfma_f32_32x32x16_bf16(vf3, pb11, acc[dt], 0, 0, 0);
        }
      }
      __builtin_amdgcn_s_setprio(0);
    }
    __syncthreads();
    buf ^= 1;
  }

  // epilogue: normalize, per-wave LDS transpose (reuse staging LDS), coalesced store
  ushort* eo = &lds[w * 32 * 136];
  float inv = 1.0f / lsum;
#pragma unroll
  for (int dt = 0; dt < 4; ++dt)
#pragma unroll
    for (int rq = 0; rq < 4; ++rq) {
      unsigned lo = cvtpk(acc[dt][4 * rq] * inv, acc[dt][4 * rq + 1] * inv);
      unsigned hh = cvtpk(acc[dt][4 * rq + 2] * inv, acc[dt][4 * rq + 3] * inv);
      uint2 pr; pr.x = lo; pr.y = hh;
      *(uint2*)&eo[l31 * 136 + dt * 32 + rq * 8 + hi * 4] = pr;
    }
  const int b = bh >> 4, h = bh & (NH - 1);
#pragma unroll
  for (int it = 0; it < 8; ++it) {
    int row = it * 4 + (lane >> 4);
    int c8 = (lane & 15) * 8;
    ushort8 v = *(const ushort8*)&eo[row * 136 + c8];
    *(ushort8*)&attnb[((size_t)b * SEQ + qsb + row) * DM + h * DK + c8] = v;
  }
}

extern "C" void kernel_launch(void* const* d_in, const int* in_sizes, int n_in,
                              void* d_out, int out_size, void* d_ws, size_t ws_size,
                              hipStream_t stream) {
  const float* x = (const float*)d_in[0];
  const int* tpos = (const int*)d_in[1];
  const float* WQ = (const float*)d_in[2];
  const float* WK = (const float*)d_in[3];
  const float* WV = (const float*)d_in[4];
  const float* WO = (const float*)d_in[5];
  float* out = (float*)d_out;
  char* ws = (char*)d_ws;

  ushort* xb  = (ushort*)(ws + 0);
  ushort* wqb = (ushort*)(ws + 16777216);
  ushort* wkb = (ushort*)(ws + 25165824);
  ushort* wvb = (ushort*)(ws + 33554432);
  ushort* wob = (ushort*)(ws + 41943040);
  ushort* Qb  = (ushort*)(ws + 50331648);
  ushort* Kb  = (ushort*)(ws + 67108864);
  ushort* Vb  = (ushort*)(ws + 83886080);
  ushort* Vt  = (ushort*)(ws + 0);           // alias xb (dead)
  ushort* attnb = (ushort*)(ws + 16777216);  // alias wqb+wkb (dead)

  cvt_kernel<<<4096, 256, 0, stream>>>(x, xb, MROWS * DM / 8);
  cvt_kernel<<<2048, 256, 0, stream>>>(WQ, wqb, DM * DM / 8);
  cvt_kernel<<<2048, 256, 0, stream>>>(WK, wkb, DM * DM / 8);
  cvt_kernel<<<2048, 256, 0, stream>>>(WV, wvb, DM * DM / 8);
  cvt_kernel<<<2048, 256, 0, stream>>>(WO, wob, DM * DM / 8);

  gemm_qkv<<<dim3(DM / 128, MROWS / 128, 3), 256, 0, stream>>>(xb, wqb, wkb, wvb, Qb, Kb, Vb);

  rope_kernel<<<4096, 256, 0, stream>>>(Qb, tpos);
  rope_kernel<<<4096, 256, 0, stream>>>(Kb, tpos);

  transpose_v<<<dim3(SEQ / 64, DK / 64, BATCH * NH), 256, 0, stream>>>(Vb, Vt);

  attn_kernel<<<dim3(512), 256, 0, stream>>>(Qb, Kb, Vt, attnb);

  gemm_out<<<dim3(DM / 128, MROWS / 128, 1), 256, 0, stream>>>(attnb, wob, out);
}

// Round 4
// 277.583 us; speedup vs baseline: 2.5811x; 1.0902x over previous
//
#include <hip/hip_runtime.h>

typedef unsigned short ushort;
typedef __attribute__((ext_vector_type(8))) __bf16 bf16x8;
typedef __attribute__((ext_vector_type(8))) ushort ushort8;
typedef __attribute__((ext_vector_type(4))) float f32x4;
typedef __attribute__((ext_vector_type(16))) float f32x16;
typedef __attribute__((ext_vector_type(4))) unsigned u32x4;

#define DM 2048
#define NH 16
#define DK 128
#define BATCH 2
#define SEQ 2048
#define MROWS (BATCH*SEQ)   // 4096

#define GLDS16(g, l) __builtin_amdgcn_global_load_lds(                         \
    (const __attribute__((address_space(1))) void*)(g),                        \
    (__attribute__((address_space(3))) void*)(l), 16, 0, 0)

__device__ __forceinline__ ushort f2bf(float f) {
  unsigned u = __builtin_bit_cast(unsigned, f);
  u += 0x7fffu + ((u >> 16) & 1u);
  return (ushort)(u >> 16);
}

__device__ __forceinline__ unsigned cvtpk(float lo, float hi) {
  unsigned r;
  asm("v_cvt_pk_bf16_f32 %0, %1, %2" : "=v"(r) : "v"(lo), "v"(hi));
  return r;
}

// ---------------- f32 -> bf16 convert (x + 4 weights, one launch) ----------------
__global__ __launch_bounds__(256) void cvt_all(const float* __restrict__ x,
                                               const float* __restrict__ w0,
                                               const float* __restrict__ w1,
                                               const float* __restrict__ w2,
                                               const float* __restrict__ w3,
                                               ushort* __restrict__ xb,
                                               ushort* __restrict__ o0,
                                               ushort* __restrict__ o1,
                                               ushort* __restrict__ o2,
                                               ushort* __restrict__ o3) {
  int b = blockIdx.x;
  const float* src;
  ushort* dst;
  int lb;
  if (b < 4096) { src = x; dst = xb; lb = b; }
  else {
    int wsel = (b - 4096) >> 11;
    lb = (b - 4096) & 2047;
    src = (wsel == 0) ? w0 : (wsel == 1) ? w1 : (wsel == 2) ? w2 : w3;
    dst = (wsel == 0) ? o0 : (wsel == 1) ? o1 : (wsel == 2) ? o2 : o3;
  }
  int i = lb * 256 + threadIdx.x;
  const float4* p = (const float4*)src;
  float4 a = p[2 * i], bq = p[2 * i + 1];
  ushort8 o;
  o[0] = f2bf(a.x); o[1] = f2bf(a.y); o[2] = f2bf(a.z); o[3] = f2bf(a.w);
  o[4] = f2bf(bq.x); o[5] = f2bf(bq.y); o[6] = f2bf(bq.z); o[7] = f2bf(bq.w);
  *(ushort8*)(dst + (size_t)8 * i) = o;
}

// ---------------- 8-phase pipelined GEMM, BM=256 BN=128 BK=64, 8 waves ----------------
// C = A(MxK) * B^T (B is NxK row-major). Triple-buffered LDS (144KB dynamic),
// counted vmcnt(6) at tile boundaries (stage tile t+2 during compute t),
// XOR-swizzled LDS granules (inverse-swizzled global source + swizzled ds_read),
// raw s_barrier (no implicit vmcnt drain), setprio around MFMA clusters.
// MODE 0: write bf16 scattered to (B,H,S,DK). MODE 1: write f32 row-major MxN.
template <int MODE>
__device__ __forceinline__ void gemm8_body(const ushort* __restrict__ A,
                                           const ushort* __restrict__ Bm,
                                           ushort* __restrict__ obf,
                                           float* __restrict__ ofp,
                                           int row0, int col0) {
  extern __shared__ ushort lds[];  // 3 bufs x (A 256x64 @0 + B 128x64 @16384)
  constexpr int NT = DM / 64;      // 32 K-tiles
  const int tid = threadIdx.x;
  const int wid = tid >> 6, lane = tid & 63;
  const int l15 = lane & 15, lhi = lane >> 4;
  const int wm = wid >> 2, wn = wid & 3;
  const int swz = l15 & 7;

  f32x4 acc[8][2];
  const f32x4 z4 = {0.f, 0.f, 0.f, 0.f};
#pragma unroll
  for (int m = 0; m < 8; ++m) { acc[m][0] = z4; acc[m][1] = z4; }

  auto stageA = [&](int kt, int h) {  // A-half h: 128 rows, 2 loads/thread
    ushort* dst = &lds[(kt % 3) * 24576 + h * 8192 + wid * 512];
    const ushort* srcb = A + (size_t)(row0 + h * 128) * DM + kt * 64;
#pragma unroll
    for (int j = 0; j < 2; ++j) {
      int idx = j * 512 + tid;
      int r = idx >> 3, c = idx & 7;
      GLDS16(srcb + (size_t)r * DM + ((c ^ (r & 7)) * 8), dst + j * 4096);
    }
  };
  auto stageB = [&](int kt) {  // B tile: 128 rows, 2 loads/thread
    ushort* dst = &lds[(kt % 3) * 24576 + 16384 + wid * 512];
    const ushort* srcb = Bm + (size_t)col0 * DM + kt * 64;
#pragma unroll
    for (int j = 0; j < 2; ++j) {
      int idx = j * 512 + tid;
      int r = idx >> 3, c = idx & 7;
      GLDS16(srcb + (size_t)r * DM + ((c ^ (r & 7)) * 8), dst + j * 4096);
    }
  };

  // prologue: stage tiles 0 and 1 (12 loads in flight), wait for tile 0
  stageA(0, 0); stageA(0, 1); stageB(0);
  stageA(1, 0); stageA(1, 1); stageB(1);
  asm volatile("s_waitcnt vmcnt(6)" ::: "memory");
  __builtin_amdgcn_s_barrier();

  for (int t = 0; t < NT; ++t) {
    const ushort* Ab = &lds[(t % 3) * 24576];
    const ushort* Bb = Ab + 16384;
    const bool pf = (t + 2 < NT);
    bf16x8 bfr[2][2];
#pragma unroll
    for (int p = 0; p < 4; ++p) {
      const int hm = p & 1, ks = p >> 1;
      bf16x8 af[4];
#pragma unroll
      for (int mq = 0; mq < 4; ++mq) {
        int row = wm * 128 + hm * 64 + mq * 16 + l15;
        af[mq] = *(const bf16x8*)&Ab[row * 64 + (((ks * 4 + lhi) ^ swz) * 8)];
      }
      if (hm == 0) {
#pragma unroll
        for (int n = 0; n < 2; ++n) {
          int row = wn * 32 + n * 16 + l15;
          bfr[ks][n] = *(const bf16x8*)&Bb[row * 64 + (((ks * 4 + lhi) ^ swz) * 8)];
        }
      }
      if (pf) {
        if (p == 0) stageA(t + 2, 0);
        else if (p == 1) stageA(t + 2, 1);
        else if (p == 2) stageB(t + 2);
      }
      __builtin_amdgcn_s_barrier();
      __builtin_amdgcn_s_setprio(1);
#pragma unroll
      for (int mq = 0; mq < 4; ++mq)
#pragma unroll
        for (int n = 0; n < 2; ++n)
          acc[hm * 4 + mq][n] = __builtin_amdgcn_mfma_f32_16x16x32_bf16(
              af[mq], bfr[ks][n], acc[hm * 4 + mq][n], 0, 0, 0);
      __builtin_amdgcn_s_setprio(0);
      if (p == 3) {
        if (pf) asm volatile("s_waitcnt vmcnt(6)" ::: "memory");
        else asm volatile("s_waitcnt vmcnt(0)" ::: "memory");
      }
      __builtin_amdgcn_s_barrier();
    }
  }

  // epilogue
#pragma unroll
  for (int m = 0; m < 8; ++m) {
    int grow = row0 + wm * 128 + m * 16 + lhi * 4;
#pragma unroll
    for (int n = 0; n < 2; ++n) {
      int gcol = col0 + wn * 32 + n * 16 + l15;
#pragma unroll
      for (int j = 0; j < 4; ++j) {
        float v = acc[m][n][j];
        int r = grow + j;
        if (MODE == 0) {
          int b = r >> 11, s = r & (SEQ - 1);
          int h = gcol >> 7, d = gcol & (DK - 1);
          obf[((size_t)(b * NH + h) * SEQ + s) * DK + d] = f2bf(v);
        } else {
          ofp[(size_t)r * DM + gcol] = v;
        }
      }
    }
  }
}

__global__ __launch_bounds__(512, 2) void gemm8_qkv(const ushort* __restrict__ A,
                                                    const ushort* __restrict__ W0,
                                                    const ushort* __restrict__ W1,
                                                    const ushort* __restrict__ W2,
                                                    ushort* __restrict__ O0,
                                                    ushort* __restrict__ O1,
                                                    ushort* __restrict__ O2) {
  // 768 blocks; XCD-bijective swizzle (768 % 8 == 0, chunk 96)
  int f = ((int)blockIdx.x & 7) * 96 + ((int)blockIdx.x >> 3);
  int z = f >> 8, rem = f & 255;
  int row0 = (rem >> 4) * 256, col0 = (rem & 15) * 128;
  const ushort* Bm = (z == 0) ? W0 : ((z == 1) ? W1 : W2);
  ushort* obf = (z == 0) ? O0 : ((z == 1) ? O1 : O2);
  gemm8_body<0>(A, Bm, obf, nullptr, row0, col0);
}

__global__ __launch_bounds__(512, 2) void gemm8_out(const ushort* __restrict__ A,
                                                    const ushort* __restrict__ Bm,
                                                    float* __restrict__ ofp) {
  // 256 blocks; chunk 32
  int f = ((int)blockIdx.x & 7) * 32 + ((int)blockIdx.x >> 3);
  int row0 = (f >> 4) * 256, col0 = (f & 15) * 128;
  gemm8_body<1>(A, Bm, nullptr, ofp, row0, col0);
}

// ---------------- RoPE in-place on (B,H,S,DK) bf16 ----------------
__global__ __launch_bounds__(256) void rope_kernel(ushort* __restrict__ buf,
                                                   const int* __restrict__ tpos) {
  int idx = blockIdx.x * 256 + threadIdx.x;
  int c = idx & 15;
  int row = idx >> 4;
  int s = row & (SEQ - 1);
  int bh = row >> 11;
  int b = bh >> 4;
  int pos = tpos[b * SEQ + s];
  int d0 = c * 8;
  ushort8 v = *(ushort8*)(buf + (size_t)row * DK + d0);
  float fp = (float)pos;
#pragma unroll
  for (int p = 0; p < 4; ++p) {
    int i = (d0 >> 1) + p;
    float freq = exp2f(-13.287712379549449f * ((float)i * (1.0f / 64.0f)));
    float ang = fp * freq;
    float sn, cs;
    sincosf(ang, &sn, &cs);
    float x1 = __builtin_bit_cast(float, (unsigned)v[2 * p] << 16);
    float x2 = __builtin_bit_cast(float, (unsigned)v[2 * p + 1] << 16);
    float r1 = x1 * cs - x2 * sn;
    float r2 = x1 * sn + x2 * cs;
    v[2 * p] = f2bf(r1);
    v[2 * p + 1] = f2bf(r2);
  }
  *(ushort8*)(buf + (size_t)row * DK + d0) = v;
}

// ---------------- V (B,H,S,DK) -> Vt (B,H,DK,S) ----------------
__global__ __launch_bounds__(256) void transpose_v(const ushort* __restrict__ Vb,
                                                   ushort* __restrict__ Vt) {
  __shared__ ushort t[64 * 80];
  int s0 = blockIdx.x * 64, d0 = blockIdx.y * 64, bh = blockIdx.z;
  const size_t base = (size_t)bh * SEQ * DK;
  int tid = threadIdx.x;
#pragma unroll
  for (int it = 0; it < 2; ++it) {
    int c = it * 256 + tid;
    int r = c >> 3, c8 = (c & 7) * 8;
    ushort8 v = *(const ushort8*)&Vb[base + (size_t)(s0 + r) * DK + d0 + c8];
    *(ushort8*)&t[r * 80 + c8] = v;
  }
  __syncthreads();
  const size_t obase = (size_t)bh * DK * SEQ;
#pragma unroll
  for (int it = 0; it < 2; ++it) {
    int c = it * 256 + tid;
    int dr = c >> 3, sc = (c & 7) * 8;
    ushort8 v;
#pragma unroll
    for (int i2 = 0; i2 < 8; ++i2) v[i2] = t[(sc + i2) * 80 + dr];
    *(ushort8*)&Vt[obase + (size_t)(d0 + dr) * SEQ + s0 + sc] = v;
  }
}

// ---------------- flash attention (causal), 4 waves/block, LDS-staged KV ----------------
__global__ __launch_bounds__(256, 2) void attn_kernel(const ushort* __restrict__ Qb,
                                                      const ushort* __restrict__ Kb,
                                                      const ushort* __restrict__ Vt,
                                                      ushort* __restrict__ attnb) {
  __shared__ ushort lds[32768];  // K bufs @0,8192; V^T bufs @16384,24576
  const int bx = blockIdx.x;
  const int u = bx & 255, hg = bx >> 8;
  const int qt = hg ? (15 - (u & 15)) : (u & 15);
  const int bh = (u >> 4) + hg * 16;
  const int tid = threadIdx.x;
  const int w = tid >> 6, lane = tid & 63;
  const int l31 = lane & 31, hi = lane >> 5;
  const int qb = qt * 128;
  const int qsb = qb + w * 32;
  const int q = qsb + l31;
  const size_t qk_base = (size_t)bh * SEQ * DK;
  const size_t v_base = (size_t)bh * DK * SEQ;
  const int nt = (qb + 128) >> 6;

  bf16x8 qf[8];
#pragma unroll
  for (int ks = 0; ks < 8; ++ks)
    qf[ks] = *(const bf16x8*)&Qb[qk_base + (size_t)q * DK + ks * 16 + hi * 8];

  f32x16 acc[4];
#pragma unroll
  for (int dt = 0; dt < 4; ++dt)
#pragma unroll
    for (int r = 0; r < 16; ++r) acc[dt][r] = 0.f;

  float m2 = -INFINITY, lsum = 0.f;
  const float cs2 = 0.08838834764831845f * 1.4426950408889634f;

  auto stage = [&](int t, int bufsel) {
    const int kb0 = t * 64;
#pragma unroll
    for (int i = 0; i < 4; ++i) {
      int g = w * 256 + i * 64 + lane;
      int row = g >> 4, c16 = g & 15;
      GLDS16(Kb + qk_base + (size_t)(kb0 + row) * DK + ((c16 ^ (row & 7)) * 8),
             &lds[bufsel * 8192 + (w * 256 + i * 64) * 8]);
    }
#pragma unroll
    for (int i = 0; i < 4; ++i) {
      int g = w * 256 + i * 64 + lane;
      int row = g >> 3, c8 = g & 7;
      GLDS16(Vt + v_base + (size_t)row * SEQ + kb0 + ((c8 ^ (row & 7)) * 8),
             &lds[16384 + bufsel * 8192 + (w * 256 + i * 64) * 8]);
    }
  };

  stage(0, 0);
  __syncthreads();
  int buf = 0;

  for (int t = 0; t < nt; ++t) {
    if (t + 1 < nt) stage(t + 1, buf ^ 1);
    const int kb0 = t * 64;
    if (kb0 <= qsb) {
      const ushort* lk = &lds[buf * 8192];
      const ushort* lv = &lds[16384 + buf * 8192];
      const int kb1 = kb0 + 32;
      const bool diag0 = (kb0 == qsb);
      const bool have1 = (kb1 <= qsb);
      const bool diag1 = (kb1 == qsb);
      const int sw = l31 & 7;

      f32x16 s0, s1;
#pragma unroll
      for (int r = 0; r < 16; ++r) { s0[r] = 0.f; s1[r] = 0.f; }
      __builtin_amdgcn_s_setprio(1);
#pragma unroll
      for (int ks = 0; ks < 8; ++ks) {
        int g = 2 * ks + hi;
        bf16x8 kf = *(const bf16x8*)&lk[(l31 * 16 + (g ^ sw)) * 8];
        s0 = __builtin_amdgcn_mfma_f32_32x32x16_bf16(kf, qf[ks], s0, 0, 0, 0);
      }
      if (have1) {
#pragma unroll
        for (int ks = 0; ks < 8; ++ks) {
          int g = 2 * ks + hi;
          bf16x8 kf = *(const bf16x8*)&lk[((32 + l31) * 16 + (g ^ sw)) * 8];
          s1 = __builtin_amdgcn_mfma_f32_32x32x16_bf16(kf, qf[ks], s1, 0, 0, 0);
        }
      }
      __builtin_amdgcn_s_setprio(0);

      float mx = -INFINITY;
#pragma unroll
      for (int r = 0; r < 16; ++r) {
        float v = s0[r] * cs2;
        if (diag0) {
          int kk = kb0 + (r & 3) + 8 * (r >> 2) + 4 * hi;
          if (kk > q) v = -INFINITY;
        }
        s0[r] = v;
        mx = fmaxf(mx, v);
      }
      if (have1) {
#pragma unroll
        for (int r = 0; r < 16; ++r) {
          float v = s1[r] * cs2;
          if (diag1) {
            int kk = kb1 + (r & 3) + 8 * (r >> 2) + 4 * hi;
            if (kk > q) v = -INFINITY;
          }
          s1[r] = v;
          mx = fmaxf(mx, v);
        }
      }
      mx = fmaxf(mx, __shfl_xor(mx, 32));

      float sc = 1.f;
      if (!__all(mx <= m2 + 11.5f)) {
        float mnew = fmaxf(m2, mx);
        sc = exp2f(m2 - mnew);
        m2 = mnew;
#pragma unroll
        for (int dt = 0; dt < 4; ++dt)
#pragma unroll
          for (int r = 0; r < 16; ++r) acc[dt][r] *= sc;
      }
      float rs = 0.f;
#pragma unroll
      for (int r = 0; r < 16; ++r) {
        float p = exp2f(s0[r] - m2);
        s0[r] = p;
        rs += p;
      }
      if (have1) {
#pragma unroll
        for (int r = 0; r < 16; ++r) {
          float p = exp2f(s1[r] - m2);
          s1[r] = p;
          rs += p;
        }
      }
      rs += __shfl_xor(rs, 32);
      lsum = lsum * sc + rs;

      unsigned w0[8], ws0[8];
#pragma unroll
      for (int i = 0; i < 8; ++i) w0[i] = cvtpk(s0[2 * i], s0[2 * i + 1]);
#pragma unroll
      for (int i = 0; i < 8; ++i) ws0[i] = (unsigned)__shfl_xor((int)w0[i], 32);
      u32x4 b00, b01;
      b00[0] = hi ? ws0[2] : w0[0]; b00[1] = hi ? ws0[3] : w0[1];
      b00[2] = hi ? w0[2] : ws0[0]; b00[3] = hi ? w0[3] : ws0[1];
      b01[0] = hi ? ws0[6] : w0[4]; b01[1] = hi ? ws0[7] : w0[5];
      b01[2] = hi ? w0[6] : ws0[4]; b01[3] = hi ? w0[7] : ws0[5];
      bf16x8 pb00 = __builtin_bit_cast(bf16x8, b00);
      bf16x8 pb01 = __builtin_bit_cast(bf16x8, b01);
      bf16x8 pb10, pb11;
      if (have1) {
        unsigned w1[8], ws1[8];
#pragma unroll
        for (int i = 0; i < 8; ++i) w1[i] = cvtpk(s1[2 * i], s1[2 * i + 1]);
#pragma unroll
        for (int i = 0; i < 8; ++i) ws1[i] = (unsigned)__shfl_xor((int)w1[i], 32);
        u32x4 b10, b11;
        b10[0] = hi ? ws1[2] : w1[0]; b10[1] = hi ? ws1[3] : w1[1];
        b10[2] = hi ? w1[2] : ws1[0]; b10[3] = hi ? w1[3] : ws1[1];
        b11[0] = hi ? ws1[6] : w1[4]; b11[1] = hi ? ws1[7] : w1[5];
        b11[2] = hi ? w1[6] : ws1[4]; b11[3] = hi ? w1[7] : ws1[5];
        pb10 = __builtin_bit_cast(bf16x8, b10);
        pb11 = __builtin_bit_cast(bf16x8, b11);
      }

      __builtin_amdgcn_s_setprio(1);
#pragma unroll
      for (int dt = 0; dt < 4; ++dt) {
        int vr = (dt * 32 + l31) * 8;
        bf16x8 vf0 = *(const bf16x8*)&lv[(vr + ((0 + hi) ^ sw)) * 8];
        bf16x8 vf1 = *(const bf16x8*)&lv[(vr + ((2 + hi) ^ sw)) * 8];
        acc[dt] = __builtin_amdgcn_mfma_f32_32x32x16_bf16(vf0, pb00, acc[dt], 0, 0, 0);
        acc[dt] = __builtin_amdgcn_mfma_f32_32x32x16_bf16(vf1, pb01, acc[dt], 0, 0, 0);
        if (have1) {
          bf16x8 vf2 = *(const bf16x8*)&lv[(vr + ((4 + hi) ^ sw)) * 8];
          bf16x8 vf3 = *(const bf16x8*)&lv[(vr + ((6 + hi) ^ sw)) * 8];
          acc[dt] = __builtin_amdgcn_mfma_f32_32x32x16_bf16(vf2, pb10, acc[dt], 0, 0, 0);
          acc[dt] = __builtin_amdgcn_mfma_f32_32x32x16_bf16(vf3, pb11, acc[dt], 0, 0, 0);
        }
      }
      __builtin_amdgcn_s_setprio(0);
    }
    __syncthreads();
    buf ^= 1;
  }

  ushort* eo = &lds[w * 32 * 136];
  float inv = 1.0f / lsum;
#pragma unroll
  for (int dt = 0; dt < 4; ++dt)
#pragma unroll
    for (int rq = 0; rq < 4; ++rq) {
      unsigned lo = cvtpk(acc[dt][4 * rq] * inv, acc[dt][4 * rq + 1] * inv);
      unsigned hh = cvtpk(acc[dt][4 * rq + 2] * inv, acc[dt][4 * rq + 3] * inv);
      uint2 pr; pr.x = lo; pr.y = hh;
      *(uint2*)&eo[l31 * 136 + dt * 32 + rq * 8 + hi * 4] = pr;
    }
  const int b = bh >> 4, h = bh & (NH - 1);
#pragma unroll
  for (int it = 0; it < 8; ++it) {
    int row = it * 4 + (lane >> 4);
    int c8 = (lane & 15) * 8;
    ushort8 v = *(const ushort8*)&eo[row * 136 + c8];
    *(ushort8*)&attnb[((size_t)b * SEQ + qsb + row) * DM + h * DK + c8] = v;
  }
}

extern "C" void kernel_launch(void* const* d_in, const int* in_sizes, int n_in,
                              void* d_out, int out_size, void* d_ws, size_t ws_size,
                              hipStream_t stream) {
  const float* x = (const float*)d_in[0];
  const int* tpos = (const int*)d_in[1];
  const float* WQ = (const float*)d_in[2];
  const float* WK = (const float*)d_in[3];
  const float* WV = (const float*)d_in[4];
  const float* WO = (const float*)d_in[5];
  float* out = (float*)d_out;
  char* ws = (char*)d_ws;

  ushort* xb  = (ushort*)(ws + 0);
  ushort* wqb = (ushort*)(ws + 16777216);
  ushort* wkb = (ushort*)(ws + 25165824);
  ushort* wvb = (ushort*)(ws + 33554432);
  ushort* wob = (ushort*)(ws + 41943040);
  ushort* Qb  = (ushort*)(ws + 50331648);
  ushort* Kb  = (ushort*)(ws + 67108864);
  ushort* Vb  = (ushort*)(ws + 83886080);
  ushort* Vt  = (ushort*)(ws + 0);           // alias xb (dead)
  ushort* attnb = (ushort*)(ws + 16777216);  // alias wqb+wkb (dead)

  hipFuncSetAttribute(reinterpret_cast<const void*>(gemm8_qkv),
                      hipFuncAttributeMaxDynamicSharedMemorySize, 147456);
  hipFuncSetAttribute(reinterpret_cast<const void*>(gemm8_out),
                      hipFuncAttributeMaxDynamicSharedMemorySize, 147456);

  cvt_all<<<12288, 256, 0, stream>>>(x, WQ, WK, WV, WO, xb, wqb, wkb, wvb, wob);

  gemm8_qkv<<<768, 512, 147456, stream>>>(xb, wqb, wkb, wvb, Qb, Kb, Vb);

  rope_kernel<<<4096, 256, 0, stream>>>(Qb, tpos);
  rope_kernel<<<4096, 256, 0, stream>>>(Kb, tpos);

  transpose_v<<<dim3(SEQ / 64, DK / 64, BATCH * NH), 256, 0, stream>>>(Vb, Vt);

  attn_kernel<<<dim3(512), 256, 0, stream>>>(Qb, Kb, Vt, attnb);

  gemm8_out<<<256, 512, 147456, stream>>>(attnb, wob, out);
}

// Round 5
// 257.745 us; speedup vs baseline: 2.7798x; 1.0770x over previous
//
#include <hip/hip_runtime.h>

typedef unsigned short ushort;
typedef __attribute__((ext_vector_type(8))) __bf16 bf16x8;
typedef __attribute__((ext_vector_type(8))) ushort ushort8;
typedef __attribute__((ext_vector_type(4))) float f32x4;
typedef __attribute__((ext_vector_type(16))) float f32x16;
typedef __attribute__((ext_vector_type(4))) unsigned u32x4;

#define DM 2048
#define NH 16
#define DK 128
#define BATCH 2
#define SEQ 2048
#define MROWS (BATCH*SEQ)   // 4096

#define GLDS16(g, l) __builtin_amdgcn_global_load_lds(                         \
    (const __attribute__((address_space(1))) void*)(g),                        \
    (__attribute__((address_space(3))) void*)(l), 16, 0, 0)

__device__ __forceinline__ ushort f2bf(float f) {
  unsigned u = __builtin_bit_cast(unsigned, f);
  u += 0x7fffu + ((u >> 16) & 1u);
  return (ushort)(u >> 16);
}

__device__ __forceinline__ unsigned cvtpk(float lo, float hi) {
  unsigned r;
  asm("v_cvt_pk_bf16_f32 %0, %1, %2" : "=v"(r) : "v"(lo), "v"(hi));
  return r;
}

// ---------------- f32 -> bf16 convert (x + 4 weights, one launch) ----------------
__global__ __launch_bounds__(256) void cvt_all(const float* __restrict__ x,
                                               const float* __restrict__ w0,
                                               const float* __restrict__ w1,
                                               const float* __restrict__ w2,
                                               const float* __restrict__ w3,
                                               ushort* __restrict__ xb,
                                               ushort* __restrict__ o0,
                                               ushort* __restrict__ o1,
                                               ushort* __restrict__ o2,
                                               ushort* __restrict__ o3) {
  int b = blockIdx.x;
  const float* src;
  ushort* dst;
  int lb;
  if (b < 4096) { src = x; dst = xb; lb = b; }
  else {
    int wsel = (b - 4096) >> 11;
    lb = (b - 4096) & 2047;
    src = (wsel == 0) ? w0 : (wsel == 1) ? w1 : (wsel == 2) ? w2 : w3;
    dst = (wsel == 0) ? o0 : (wsel == 1) ? o1 : (wsel == 2) ? o2 : o3;
  }
  int i = lb * 256 + threadIdx.x;
  const float4* p = (const float4*)src;
  float4 a = p[2 * i], bq = p[2 * i + 1];
  ushort8 o;
  o[0] = f2bf(a.x); o[1] = f2bf(a.y); o[2] = f2bf(a.z); o[3] = f2bf(a.w);
  o[4] = f2bf(bq.x); o[5] = f2bf(bq.y); o[6] = f2bf(bq.z); o[7] = f2bf(bq.w);
  *(ushort8*)(dst + (size_t)8 * i) = o;
}

// ---------------- fused multi-weight GEMM, BM=128, BK=64, 8 waves (2M x 4N) ----------------
// C_w = A(MxK) * B_w^T for NW weights sharing A. Wave-tile 64 x (NFR*16) per weight.
// Double-buffered LDS; stage(t+1) issued at tile start (loads in flight across both
// ks-phases); ONE vmcnt(0) + s_barrier per K-tile. XOR-swizzled LDS granules
// (inverse-swizzled global source + swizzled ds_read). setprio around MFMA clusters.
// MODE 0: write bf16 scattered to (B,H,S,DK) per weight. MODE 1: write f32 MxN.
template <int NW, int NFR, int MODE>
__device__ __forceinline__ void gemmF_body(const ushort* __restrict__ A,
                                           const ushort* __restrict__ B0,
                                           const ushort* __restrict__ B1,
                                           const ushort* __restrict__ B2,
                                           ushort* __restrict__ O0,
                                           ushort* __restrict__ O1,
                                           ushort* __restrict__ O2,
                                           float* __restrict__ ofp,
                                           int row0, int col0) {
  extern __shared__ ushort lds[];
  constexpr int NT = DM / 64;                       // 32 K-tiles
  constexpr int BUFSZ = 8192 + NW * NFR * 4096;     // ushorts per buffer
  const ushort* Bw[3] = {B0, B1, B2};
  ushort* Ow[3] = {O0, O1, O2};
  const int tid = threadIdx.x;
  const int wid = tid >> 6, lane = tid & 63;
  const int l15 = lane & 15, lhi = lane >> 4;
  const int wm = wid >> 2, wn = wid & 3;
  const int swz = l15 & 7;

  f32x4 acc[4][NW * NFR];
  const f32x4 z4 = {0.f, 0.f, 0.f, 0.f};
#pragma unroll
  for (int mq = 0; mq < 4; ++mq)
#pragma unroll
    for (int i = 0; i < NW * NFR; ++i) acc[mq][i] = z4;

  auto stage = [&](int kt, int buf) {
    ushort* dstA = &lds[buf * BUFSZ];
    const ushort* srcA = A + (size_t)row0 * DM + kt * 64;
#pragma unroll
    for (int j = 0; j < 2; ++j) {
      int g = j * 512 + tid;
      int r = g >> 3, c = g & 7;
      GLDS16(srcA + (size_t)r * DM + ((c ^ (r & 7)) * 8),
             &dstA[(j * 512 + wid * 64) * 8]);
    }
#pragma unroll
    for (int w3 = 0; w3 < NW; ++w3) {
      ushort* dstB = &lds[buf * BUFSZ + 8192 + w3 * NFR * 4096];
      const ushort* srcB = Bw[w3] + (size_t)col0 * DM + kt * 64;
#pragma unroll
      for (int j = 0; j < NFR; ++j) {
        int g = j * 512 + tid;
        int r = g >> 3, c = g & 7;
        GLDS16(srcB + (size_t)r * DM + ((c ^ (r & 7)) * 8),
               &dstB[(j * 512 + wid * 64) * 8]);
      }
    }
  };

  stage(0, 0);
  asm volatile("s_waitcnt vmcnt(0)" ::: "memory");
  asm volatile("s_barrier" ::: "memory");

  for (int t = 0; t < NT; ++t) {
    const int cb = t & 1;
    const ushort* Ab = &lds[cb * BUFSZ];
    const ushort* Bb = Ab + 8192;
    if (t + 1 < NT) stage(t + 1, cb ^ 1);
#pragma unroll
    for (int ks = 0; ks < 2; ++ks) {
      bf16x8 af[4];
#pragma unroll
      for (int mq = 0; mq < 4; ++mq) {
        int row = wm * 64 + mq * 16 + l15;
        af[mq] = *(const bf16x8*)&Ab[row * 64 + (((ks * 4 + lhi) ^ swz) * 8)];
      }
      bf16x8 bfr[NW * NFR];
#pragma unroll
      for (int w3 = 0; w3 < NW; ++w3)
#pragma unroll
        for (int n = 0; n < NFR; ++n) {
          int row = wn * (NFR * 16) + n * 16 + l15;
          bfr[w3 * NFR + n] =
              *(const bf16x8*)&Bb[w3 * NFR * 4096 + row * 64 + (((ks * 4 + lhi) ^ swz) * 8)];
        }
      __builtin_amdgcn_s_setprio(1);
#pragma unroll
      for (int mq = 0; mq < 4; ++mq)
#pragma unroll
        for (int i = 0; i < NW * NFR; ++i)
          acc[mq][i] = __builtin_amdgcn_mfma_f32_16x16x32_bf16(af[mq], bfr[i], acc[mq][i], 0, 0, 0);
      __builtin_amdgcn_s_setprio(0);
    }
    asm volatile("s_waitcnt vmcnt(0)" ::: "memory");
    asm volatile("s_barrier" ::: "memory");
  }

  // epilogue
#pragma unroll
  for (int mq = 0; mq < 4; ++mq) {
    int grow = row0 + wm * 64 + mq * 16 + lhi * 4;
#pragma unroll
    for (int w3 = 0; w3 < NW; ++w3)
#pragma unroll
      for (int n = 0; n < NFR; ++n) {
        int gcol = col0 + wn * (NFR * 16) + n * 16 + l15;
#pragma unroll
        for (int j = 0; j < 4; ++j) {
          float v = acc[mq][w3 * NFR + n][j];
          int r = grow + j;
          if (MODE == 0) {
            int b = r >> 11, s = r & (SEQ - 1);
            int h = gcol >> 7, d = gcol & (DK - 1);
            Ow[w3][((size_t)(b * NH + h) * SEQ + s) * DK + d] = f2bf(v);
          } else {
            ofp[(size_t)r * DM + gcol] = v;
          }
        }
      }
  }
}

__global__ __launch_bounds__(512, 2) void gemmF_qkv(const ushort* __restrict__ A,
                                                    const ushort* __restrict__ W0,
                                                    const ushort* __restrict__ W1,
                                                    const ushort* __restrict__ W2,
                                                    ushort* __restrict__ O0,
                                                    ushort* __restrict__ O1,
                                                    ushort* __restrict__ O2) {
  // 512 blocks; XCD-bijective swizzle (512 % 8 == 0, chunk 64)
  int f = ((int)blockIdx.x & 7) * 64 + ((int)blockIdx.x >> 3);
  int row0 = (f >> 4) * 128, col0 = (f & 15) * 128;
  gemmF_body<3, 2, 0>(A, W0, W1, W2, O0, O1, O2, nullptr, row0, col0);
}

__global__ __launch_bounds__(512, 2) void gemmF_out(const ushort* __restrict__ A,
                                                    const ushort* __restrict__ Bm,
                                                    float* __restrict__ ofp) {
  // 256 blocks; chunk 32
  int f = ((int)blockIdx.x & 7) * 32 + ((int)blockIdx.x >> 3);
  int row0 = (f >> 3) * 128, col0 = (f & 7) * 256;
  gemmF_body<1, 4, 1>(A, Bm, nullptr, nullptr, nullptr, nullptr, nullptr, ofp, row0, col0);
}

// ---------------- RoPE in-place on Q and K, (B,H,S,DK) bf16, one launch ----------------
__global__ __launch_bounds__(256) void rope_kernel(ushort* __restrict__ Q,
                                                   ushort* __restrict__ K,
                                                   const int* __restrict__ tpos) {
  int bid = blockIdx.x;
  ushort* buf = (bid & 1) ? K : Q;
  int idx = (bid >> 1) * 256 + threadIdx.x;
  int c = idx & 15;
  int row = idx >> 4;
  int s = row & (SEQ - 1);
  int bh = row >> 11;
  int b = bh >> 4;
  int pos = tpos[b * SEQ + s];
  int d0 = c * 8;
  ushort8 v = *(ushort8*)(buf + (size_t)row * DK + d0);
  float fp = (float)pos;
#pragma unroll
  for (int p = 0; p < 4; ++p) {
    int i = (d0 >> 1) + p;
    float freq = exp2f(-13.287712379549449f * ((float)i * (1.0f / 64.0f)));
    float ang = fp * freq;
    float sn, cs;
    sincosf(ang, &sn, &cs);
    float x1 = __builtin_bit_cast(float, (unsigned)v[2 * p] << 16);
    float x2 = __builtin_bit_cast(float, (unsigned)v[2 * p + 1] << 16);
    float r1 = x1 * cs - x2 * sn;
    float r2 = x1 * sn + x2 * cs;
    v[2 * p] = f2bf(r1);
    v[2 * p + 1] = f2bf(r2);
  }
  *(ushort8*)(buf + (size_t)row * DK + d0) = v;
}

// ---------------- V (B,H,S,DK) -> Vt (B,H,DK,S) ----------------
__global__ __launch_bounds__(256) void transpose_v(const ushort* __restrict__ Vb,
                                                   ushort* __restrict__ Vt) {
  __shared__ ushort t[64 * 80];
  int s0 = blockIdx.x * 64, d0 = blockIdx.y * 64, bh = blockIdx.z;
  const size_t base = (size_t)bh * SEQ * DK;
  int tid = threadIdx.x;
#pragma unroll
  for (int it = 0; it < 2; ++it) {
    int c = it * 256 + tid;
    int r = c >> 3, c8 = (c & 7) * 8;
    ushort8 v = *(const ushort8*)&Vb[base + (size_t)(s0 + r) * DK + d0 + c8];
    *(ushort8*)&t[r * 80 + c8] = v;
  }
  __syncthreads();
  const size_t obase = (size_t)bh * DK * SEQ;
#pragma unroll
  for (int it = 0; it < 2; ++it) {
    int c = it * 256 + tid;
    int dr = c >> 3, sc = (c & 7) * 8;
    ushort8 v;
#pragma unroll
    for (int i2 = 0; i2 < 8; ++i2) v[i2] = t[(sc + i2) * 80 + dr];
    *(ushort8*)&Vt[obase + (size_t)(d0 + dr) * SEQ + s0 + sc] = v;
  }
}

// ---------------- flash attention (causal), 4 waves/block, LDS-staged KV ----------------
__global__ __launch_bounds__(256, 2) void attn_kernel(const ushort* __restrict__ Qb,
                                                      const ushort* __restrict__ Kb,
                                                      const ushort* __restrict__ Vt,
                                                      ushort* __restrict__ attnb) {
  __shared__ ushort lds[32768];  // K bufs @0,8192; V^T bufs @16384,24576
  const int bx = blockIdx.x;
  const int u = bx & 255, hg = bx >> 8;
  const int qt = hg ? (15 - (u & 15)) : (u & 15);
  const int bh = (u >> 4) + hg * 16;
  const int tid = threadIdx.x;
  const int w = tid >> 6, lane = tid & 63;
  const int l31 = lane & 31, hi = lane >> 5;
  const int qb = qt * 128;
  const int qsb = qb + w * 32;
  const int q = qsb + l31;
  const size_t qk_base = (size_t)bh * SEQ * DK;
  const size_t v_base = (size_t)bh * DK * SEQ;
  const int nt = (qb + 128) >> 6;

  bf16x8 qf[8];
#pragma unroll
  for (int ks = 0; ks < 8; ++ks)
    qf[ks] = *(const bf16x8*)&Qb[qk_base + (size_t)q * DK + ks * 16 + hi * 8];

  f32x16 acc[4];
#pragma unroll
  for (int dt = 0; dt < 4; ++dt)
#pragma unroll
    for (int r = 0; r < 16; ++r) acc[dt][r] = 0.f;

  float m2 = -INFINITY, lsum = 0.f;
  const float cs2 = 0.08838834764831845f * 1.4426950408889634f;

  auto stage = [&](int t, int bufsel) {
    const int kb0 = t * 64;
#pragma unroll
    for (int i = 0; i < 4; ++i) {
      int g = w * 256 + i * 64 + lane;
      int row = g >> 4, c16 = g & 15;
      GLDS16(Kb + qk_base + (size_t)(kb0 + row) * DK + ((c16 ^ (row & 7)) * 8),
             &lds[bufsel * 8192 + (w * 256 + i * 64) * 8]);
    }
#pragma unroll
    for (int i = 0; i < 4; ++i) {
      int g = w * 256 + i * 64 + lane;
      int row = g >> 3, c8 = g & 7;
      GLDS16(Vt + v_base + (size_t)row * SEQ + kb0 + ((c8 ^ (row & 7)) * 8),
             &lds[16384 + bufsel * 8192 + (w * 256 + i * 64) * 8]);
    }
  };

  stage(0, 0);
  __syncthreads();
  int buf = 0;

  for (int t = 0; t < nt; ++t) {
    if (t + 1 < nt) stage(t + 1, buf ^ 1);
    const int kb0 = t * 64;
    if (kb0 <= qsb) {
      const ushort* lk = &lds[buf * 8192];
      const ushort* lv = &lds[16384 + buf * 8192];
      const int kb1 = kb0 + 32;
      const bool diag0 = (kb0 == qsb);
      const bool have1 = (kb1 <= qsb);
      const bool diag1 = (kb1 == qsb);
      const int sw = l31 & 7;

      f32x16 s0, s1;
#pragma unroll
      for (int r = 0; r < 16; ++r) { s0[r] = 0.f; s1[r] = 0.f; }
      __builtin_amdgcn_s_setprio(1);
#pragma unroll
      for (int ks = 0; ks < 8; ++ks) {
        int g = 2 * ks + hi;
        bf16x8 kf = *(const bf16x8*)&lk[(l31 * 16 + (g ^ sw)) * 8];
        s0 = __builtin_amdgcn_mfma_f32_32x32x16_bf16(kf, qf[ks], s0, 0, 0, 0);
      }
      if (have1) {
#pragma unroll
        for (int ks = 0; ks < 8; ++ks) {
          int g = 2 * ks + hi;
          bf16x8 kf = *(const bf16x8*)&lk[((32 + l31) * 16 + (g ^ sw)) * 8];
          s1 = __builtin_amdgcn_mfma_f32_32x32x16_bf16(kf, qf[ks], s1, 0, 0, 0);
        }
      }
      __builtin_amdgcn_s_setprio(0);

      float mx = -INFINITY;
#pragma unroll
      for (int r = 0; r < 16; ++r) {
        float v = s0[r] * cs2;
        if (diag0) {
          int kk = kb0 + (r & 3) + 8 * (r >> 2) + 4 * hi;
          if (kk > q) v = -INFINITY;
        }
        s0[r] = v;
        mx = fmaxf(mx, v);
      }
      if (have1) {
#pragma unroll
        for (int r = 0; r < 16; ++r) {
          float v = s1[r] * cs2;
          if (diag1) {
            int kk = kb1 + (r & 3) + 8 * (r >> 2) + 4 * hi;
            if (kk > q) v = -INFINITY;
          }
          s1[r] = v;
          mx = fmaxf(mx, v);
        }
      }
      mx = fmaxf(mx, __shfl_xor(mx, 32));

      float sc = 1.f;
      if (!__all(mx <= m2 + 11.5f)) {
        float mnew = fmaxf(m2, mx);
        sc = exp2f(m2 - mnew);
        m2 = mnew;
#pragma unroll
        for (int dt = 0; dt < 4; ++dt)
#pragma unroll
          for (int r = 0; r < 16; ++r) acc[dt][r] *= sc;
      }
      float rs = 0.f;
#pragma unroll
      for (int r = 0; r < 16; ++r) {
        float p = exp2f(s0[r] - m2);
        s0[r] = p;
        rs += p;
      }
      if (have1) {
#pragma unroll
        for (int r = 0; r < 16; ++r) {
          float p = exp2f(s1[r] - m2);
          s1[r] = p;
          rs += p;
        }
      }
      rs += __shfl_xor(rs, 32);
      lsum = lsum * sc + rs;

      unsigned w0[8], ws0[8];
#pragma unroll
      for (int i = 0; i < 8; ++i) w0[i] = cvtpk(s0[2 * i], s0[2 * i + 1]);
#pragma unroll
      for (int i = 0; i < 8; ++i) ws0[i] = (unsigned)__shfl_xor((int)w0[i], 32);
      u32x4 b00, b01;
      b00[0] = hi ? ws0[2] : w0[0]; b00[1] = hi ? ws0[3] : w0[1];
      b00[2] = hi ? w0[2] : ws0[0]; b00[3] = hi ? w0[3] : ws0[1];
      b01[0] = hi ? ws0[6] : w0[4]; b01[1] = hi ? ws0[7] : w0[5];
      b01[2] = hi ? w0[6] : ws0[4]; b01[3] = hi ? w0[7] : ws0[5];
      bf16x8 pb00 = __builtin_bit_cast(bf16x8, b00);
      bf16x8 pb01 = __builtin_bit_cast(bf16x8, b01);
      bf16x8 pb10, pb11;
      if (have1) {
        unsigned w1[8], ws1[8];
#pragma unroll
        for (int i = 0; i < 8; ++i) w1[i] = cvtpk(s1[2 * i], s1[2 * i + 1]);
#pragma unroll
        for (int i = 0; i < 8; ++i) ws1[i] = (unsigned)__shfl_xor((int)w1[i], 32);
        u32x4 b10, b11;
        b10[0] = hi ? ws1[2] : w1[0]; b10[1] = hi ? ws1[3] : w1[1];
        b10[2] = hi ? w1[2] : ws1[0]; b10[3] = hi ? w1[3] : ws1[1];
        b11[0] = hi ? ws1[6] : w1[4]; b11[1] = hi ? ws1[7] : w1[5];
        b11[2] = hi ? w1[6] : ws1[4]; b11[3] = hi ? w1[7] : ws1[5];
        pb10 = __builtin_bit_cast(bf16x8, b10);
        pb11 = __builtin_bit_cast(bf16x8, b11);
      }

      __builtin_amdgcn_s_setprio(1);
#pragma unroll
      for (int dt = 0; dt < 4; ++dt) {
        int vr = (dt * 32 + l31) * 8;
        bf16x8 vf0 = *(const bf16x8*)&lv[(vr + ((0 + hi) ^ sw)) * 8];
        bf16x8 vf1 = *(const bf16x8*)&lv[(vr + ((2 + hi) ^ sw)) * 8];
        acc[dt] = __builtin_amdgcn_mfma_f32_32x32x16_bf16(vf0, pb00, acc[dt], 0, 0, 0);
        acc[dt] = __builtin_amdgcn_mfma_f32_32x32x16_bf16(vf1, pb01, acc[dt], 0, 0, 0);
        if (have1) {
          bf16x8 vf2 = *(const bf16x8*)&lv[(vr + ((4 + hi) ^ sw)) * 8];
          bf16x8 vf3 = *(const bf16x8*)&lv[(vr + ((6 + hi) ^ sw)) * 8];
          acc[dt] = __builtin_amdgcn_mfma_f32_32x32x16_bf16(vf2, pb10, acc[dt], 0, 0, 0);
          acc[dt] = __builtin_amdgcn_mfma_f32_32x32x16_bf16(vf3, pb11, acc[dt], 0, 0, 0);
        }
      }
      __builtin_amdgcn_s_setprio(0);
    }
    __syncthreads();
    buf ^= 1;
  }

  ushort* eo = &lds[w * 32 * 136];
  float inv = 1.0f / lsum;
#pragma unroll
  for (int dt = 0; dt < 4; ++dt)
#pragma unroll
    for (int rq = 0; rq < 4; ++rq) {
      unsigned lo = cvtpk(acc[dt][4 * rq] * inv, acc[dt][4 * rq + 1] * inv);
      unsigned hh = cvtpk(acc[dt][4 * rq + 2] * inv, acc[dt][4 * rq + 3] * inv);
      uint2 pr; pr.x = lo; pr.y = hh;
      *(uint2*)&eo[l31 * 136 + dt * 32 + rq * 8 + hi * 4] = pr;
    }
  const int b = bh >> 4, h = bh & (NH - 1);
#pragma unroll
  for (int it = 0; it < 8; ++it) {
    int row = it * 4 + (lane >> 4);
    int c8 = (lane & 15) * 8;
    ushort8 v = *(const ushort8*)&eo[row * 136 + c8];
    *(ushort8*)&attnb[((size_t)b * SEQ + qsb + row) * DM + h * DK + c8] = v;
  }
}

extern "C" void kernel_launch(void* const* d_in, const int* in_sizes, int n_in,
                              void* d_out, int out_size, void* d_ws, size_t ws_size,
                              hipStream_t stream) {
  const float* x = (const float*)d_in[0];
  const int* tpos = (const int*)d_in[1];
  const float* WQ = (const float*)d_in[2];
  const float* WK = (const float*)d_in[3];
  const float* WV = (const float*)d_in[4];
  const float* WO = (const float*)d_in[5];
  float* out = (float*)d_out;
  char* ws = (char*)d_ws;

  ushort* xb  = (ushort*)(ws + 0);
  ushort* wqb = (ushort*)(ws + 16777216);
  ushort* wkb = (ushort*)(ws + 25165824);
  ushort* wvb = (ushort*)(ws + 33554432);
  ushort* wob = (ushort*)(ws + 41943040);
  ushort* Qb  = (ushort*)(ws + 50331648);
  ushort* Kb  = (ushort*)(ws + 67108864);
  ushort* Vb  = (ushort*)(ws + 83886080);
  ushort* Vt  = (ushort*)(ws + 0);           // alias xb (dead)
  ushort* attnb = (ushort*)(ws + 16777216);  // alias wqb+wkb (dead)

  hipFuncSetAttribute(reinterpret_cast<const void*>(gemmF_qkv),
                      hipFuncAttributeMaxDynamicSharedMemorySize, 131072);
  hipFuncSetAttribute(reinterpret_cast<const void*>(gemmF_out),
                      hipFuncAttributeMaxDynamicSharedMemorySize, 98304);

  cvt_all<<<12288, 256, 0, stream>>>(x, WQ, WK, WV, WO, xb, wqb, wkb, wvb, wob);

  gemmF_qkv<<<512, 512, 131072, stream>>>(xb, wqb, wkb, wvb, Qb, Kb, Vb);

  rope_kernel<<<8192, 256, 0, stream>>>(Qb, Kb, tpos);

  transpose_v<<<dim3(SEQ / 64, DK / 64, BATCH * NH), 256, 0, stream>>>(Vb, Vt);

  attn_kernel<<<dim3(512), 256, 0, stream>>>(Qb, Kb, Vt, attnb);

  gemmF_out<<<256, 512, 98304, stream>>>(attnb, wob, out);
}